// Round 1
// baseline (906.220 us; speedup 1.0000x reference)
//
#include <hip/hip_runtime.h>
#include <hip/hip_bf16.h>
#include <stdint.h>

#define EPSF 1e-8f

typedef __attribute__((ext_vector_type(8))) short short8;
typedef __attribute__((ext_vector_type(4))) float floatx4;

__device__ __forceinline__ unsigned short f2bf(float f) {
    union { float f; unsigned u; } c; c.f = f;
    unsigned u = c.u;
    unsigned r = u >> 16;
    unsigned rem = u & 0xffffu;
    r += (rem > 0x8000u) || ((rem == 0x8000u) && (r & 1u));
    return (unsigned short)r;
}
__device__ __forceinline__ float bf2f(unsigned short h) {
    union { unsigned u; float f; } c; c.u = ((unsigned)h) << 16;
    return c.f;
}

// ---------------- elementwise conversion kernels ----------------

__global__ void split_kernel(const float* __restrict__ in,
                             unsigned short* __restrict__ hi,
                             unsigned short* __restrict__ lo, int n) {
    int i = blockIdx.x * blockDim.x + threadIdx.x;
    if (i >= n) return;
    float f = in[i];
    unsigned short h = f2bf(f);
    hi[i] = h;
    lo[i] = f2bf(f - bf2f(h));
}

__global__ void cvt_kernel(const float* __restrict__ in,
                           unsigned short* __restrict__ out, int n) {
    int i = blockIdx.x * blockDim.x + threadIdx.x;
    if (i >= n) return;
    out[i] = f2bf(in[i]);
}

// ---------------- MFMA GEMM (C = A * B^T + bias), bf16 inputs ----------------
// A: M x K row-major (bf16 bits in ushort), B: N x K row-major, C: M x N fp32.
// SPLIT: A = Ah + Al, B = Bh + Bl (hi/lo bf16 split of fp32), 3 MFMAs/k-step.

__device__ __forceinline__ void gld16(const unsigned short* g, unsigned short* l) {
    __builtin_amdgcn_global_load_lds(
        (const __attribute__((address_space(1))) unsigned int*)g,
        (__attribute__((address_space(3))) unsigned int*)l, 16, 0, 0);
}

template <bool SPLIT>
__global__ __launch_bounds__(256)
void gemm_bt(const unsigned short* __restrict__ Ah, const unsigned short* __restrict__ Al,
             const unsigned short* __restrict__ Bh, const unsigned short* __restrict__ Bl,
             const float* __restrict__ bias, float* __restrict__ C,
             int M, int N, int K) {
    constexpr int BM = 128, BN = 128, BK = 32;
    extern __shared__ unsigned short smem[];
    unsigned short* sAh = smem;             // BM*BK = 4096 elements
    unsigned short* sBh = smem + 4096;
    unsigned short* sAl = smem + 8192;      // used only when SPLIT
    unsigned short* sBl = smem + 12288;

    const int tid  = threadIdx.x;
    const int lane = tid & 63;
    const int wid  = tid >> 6;
    const int wr   = wid >> 1, wc = wid & 1;
    const int m16  = lane & 15, quad = lane >> 4;

    const int rowA0 = blockIdx.y * BM;
    const int rowB0 = blockIdx.x * BN;

    floatx4 acc[4][4];
#pragma unroll
    for (int i = 0; i < 4; i++)
#pragma unroll
        for (int j = 0; j < 4; j++) acc[i][j] = (floatx4){0.f, 0.f, 0.f, 0.f};

    const int nk = K / BK;
    for (int kt = 0; kt < nk; ++kt) {
        const int k0 = kt * BK;
#pragma unroll
        for (int i = 0; i < 2; i++) {
            int c  = tid + 256 * i;       // 0..511 chunk id; 16B per chunk
            int r  = c >> 2;              // tile row 0..127
            int cc = c & 3;               // 16B column chunk within row
            gld16(Ah + (size_t)(rowA0 + r) * K + k0 + cc * 8, sAh + c * 8);
            gld16(Bh + (size_t)(rowB0 + r) * K + k0 + cc * 8, sBh + c * 8);
            if (SPLIT) {
                gld16(Al + (size_t)(rowA0 + r) * K + k0 + cc * 8, sAl + c * 8);
                gld16(Bl + (size_t)(rowB0 + r) * K + k0 + cc * 8, sBl + c * 8);
            }
        }
        __syncthreads();

        short8 a[4], b[4], al[4], bl[4];
#pragma unroll
        for (int i = 0; i < 4; i++) {
            a[i] = *(const short8*)(sAh + (wr * 64 + i * 16 + m16) * BK + quad * 8);
            b[i] = *(const short8*)(sBh + (wc * 64 + i * 16 + m16) * BK + quad * 8);
            if (SPLIT) {
                al[i] = *(const short8*)(sAl + (wr * 64 + i * 16 + m16) * BK + quad * 8);
                bl[i] = *(const short8*)(sBl + (wc * 64 + i * 16 + m16) * BK + quad * 8);
            }
        }
#pragma unroll
        for (int i = 0; i < 4; i++)
#pragma unroll
            for (int j = 0; j < 4; j++) {
                acc[i][j] = __builtin_amdgcn_mfma_f32_16x16x32_bf16(a[i], b[j], acc[i][j], 0, 0, 0);
                if (SPLIT) {
                    acc[i][j] = __builtin_amdgcn_mfma_f32_16x16x32_bf16(a[i], bl[j], acc[i][j], 0, 0, 0);
                    acc[i][j] = __builtin_amdgcn_mfma_f32_16x16x32_bf16(al[i], b[j], acc[i][j], 0, 0, 0);
                }
            }
        __syncthreads();
    }

    // epilogue: C/D layout col=lane&15, row=quad*4+reg (verified m89/m91)
#pragma unroll
    for (int i = 0; i < 4; i++) {
#pragma unroll
        for (int j = 0; j < 4; j++) {
            int col  = rowB0 + wc * 64 + j * 16 + m16;
            float bv = bias[col];
#pragma unroll
            for (int r = 0; r < 4; r++) {
                int row = rowA0 + wr * 64 + i * 16 + quad * 4 + r;
                C[(size_t)row * N + col] = acc[i][j][r] + bv;
            }
        }
    }
}

// ---------------- sequential quaternion scan ----------------
// v: (B,S,3H) fp32.  states out: (B,S,4H) bf16 bits.  m_final: (B,H,4) fp32.
// One thread per (b,h) chain; 8-step register chunks, double-buffered prefetch.

__global__ __launch_bounds__(64)
void scan_kernel(const float* __restrict__ v, unsigned short* __restrict__ st,
                 float* __restrict__ m_final, int S, int H) {
    const int t = blockIdx.x * blockDim.x + threadIdx.x;  // chain id in [0, B*H)
    const int b = t >> 10;   // H == 1024
    const int h = t & 1023;
    const size_t vstep = (size_t)3 * H;
    const size_t sstep = (size_t)4 * H;
    const float* vp = v + (size_t)b * S * vstep + (size_t)h * 3;
    unsigned short* sp = st + (size_t)b * S * sstep + (size_t)h * 4;

    float mw = 1.f, mx = 0.f, my = 0.f, mz = 0.f;

    constexpr int CH = 8;
    float ax[CH], ay[CH], az[CH], bx[CH], by[CH], bz[CH];

#pragma unroll
    for (int i = 0; i < CH; ++i) {
        ax[i] = vp[i * vstep + 0];
        ay[i] = vp[i * vstep + 1];
        az[i] = vp[i * vstep + 2];
    }

    auto step = [&](float vx, float vy, float vz) {
        float t2 = vx * vx + vy * vy + vz * vz;
        float th = sqrtf(t2);
        float s_, c_;
        __sincosf(th, &s_, &c_);
        float k  = __fdividef(s_, th + EPSF);
        float qw = c_, qx = k * vx, qy = k * vy, qz = k * vz;
        float nw = qw * mw - qx * mx - qy * my - qz * mz;
        float nx = qw * mx + qx * mw + qy * mz - qz * my;
        float ny = qw * my - qx * mz + qy * mw + qz * mx;
        float nz = qw * mz + qx * my - qy * mx + qz * mw;
        float nn  = nw * nw + nx * nx + ny * ny + nz * nz;
        float inv = __frsqrt_rn(nn);   // == 1/(|n|+1e-8) to ~1e-8 since |n|~1
        mw = nw * inv; mx = nx * inv; my = ny * inv; mz = nz * inv;
        ushort4 u;
        u.x = f2bf(mw); u.y = f2bf(mx); u.z = f2bf(my); u.w = f2bf(mz);
        *(ushort4*)sp = u;
        sp += sstep;
    };

    const int NC = S / CH;  // 256 chunks
    for (int c = 0; c < NC; c += 2) {
        if (c + 1 < NC) {
            const float* vb = vp + (size_t)(c + 1) * CH * vstep;
#pragma unroll
            for (int i = 0; i < CH; ++i) {
                bx[i] = vb[i * vstep + 0];
                by[i] = vb[i * vstep + 1];
                bz[i] = vb[i * vstep + 2];
            }
        }
#pragma unroll
        for (int i = 0; i < CH; ++i) step(ax[i], ay[i], az[i]);
        if (c + 2 < NC) {
            const float* va = vp + (size_t)(c + 2) * CH * vstep;
#pragma unroll
            for (int i = 0; i < CH; ++i) {
                ax[i] = va[i * vstep + 0];
                ay[i] = va[i * vstep + 1];
                az[i] = va[i * vstep + 2];
            }
        }
#pragma unroll
        for (int i = 0; i < CH; ++i) step(bx[i], by[i], bz[i]);
    }

    float* mf = m_final + (size_t)t * 4;
    mf[0] = mw; mf[1] = mx; mf[2] = my; mf[3] = mz;
}

// ---------------- launch ----------------

extern "C" void kernel_launch(void* const* d_in, const int* in_sizes, int n_in,
                              void* d_out, int out_size, void* d_ws, size_t ws_size,
                              hipStream_t stream) {
    const float* x     = (const float*)d_in[0];
    const float* W_in  = (const float*)d_in[1];
    const float* b_in  = (const float*)d_in[2];
    const float* W_out = (const float*)d_in[3];
    const float* b_out = (const float*)d_in[4];
    float* out = (float*)d_out;

    const int B = 4, S = 2048, D = 1024, H = 1024;
    const int M  = B * S;    // 8192
    const int N1 = 3 * H;    // 3072
    const int K1 = D;        // 1024
    const int N2 = D;        // 1024
    const int K2 = 4 * H;    // 4096

    // workspace layout (bytes):
    //   [0, 100663296)            v            fp32 M*N1
    //   [100663296, 167772160)    states bf16  M*K2   (also hosts split bufs
    //                                          consumed by GEMM1 before scan)
    //   [167772160, 176160768)    W_out bf16   N2*K2
    char* ws = (char*)d_ws;
    float*          v   = (float*)(ws);
    unsigned short* st  = (unsigned short*)(ws + 100663296u);
    unsigned short* woh = (unsigned short*)(ws + 167772160u);
    unsigned short* xh  = (unsigned short*)(ws + 100663296u);
    unsigned short* xl  = (unsigned short*)(ws + 100663296u + 16777216u);
    unsigned short* wih = (unsigned short*)(ws + 100663296u + 33554432u);
    unsigned short* wil = (unsigned short*)(ws + 100663296u + 33554432u + 6291456u);

    const int nx  = M * K1;    // 8388608
    const int nw  = N1 * K1;   // 3145728
    const int nwo = N2 * K2;   // 4194304

    split_kernel<<<(nx + 255) / 256, 256, 0, stream>>>(x, xh, xl, nx);
    split_kernel<<<(nw + 255) / 256, 256, 0, stream>>>(W_in, wih, wil, nw);
    cvt_kernel<<<(nwo + 255) / 256, 256, 0, stream>>>(W_out, woh, nwo);

    // v = x @ W_in^T + b_in   (split-bf16, fp32-accurate)
    gemm_bt<true><<<dim3(N1 / 128, M / 128), 256, 32768, stream>>>(
        xh, xl, wih, wil, b_in, v, M, N1, K1);

    // sequential quaternion scan; writes states (bf16) + m_final (fp32)
    scan_kernel<<<(B * H) / 64, 64, 0, stream>>>(v, st, out + (size_t)M * D, S, H);

    // out = states @ W_out^T + b_out
    gemm_bt<false><<<dim3(N2 / 128, M / 128), 256, 16384, stream>>>(
        st, nullptr, woh, nullptr, b_out, out, M, N2, K2);
}

// Round 2
// 655.881 us; speedup vs baseline: 1.3817x; 1.3817x over previous
//
#include <hip/hip_runtime.h>
#include <hip/hip_bf16.h>
#include <stdint.h>

#define EPSF 1e-8f

typedef __attribute__((ext_vector_type(8))) short short8;
typedef __attribute__((ext_vector_type(4))) float floatx4;

__device__ __forceinline__ unsigned short f2bf(float f) {
    union { float f; unsigned u; } c; c.f = f;
    unsigned u = c.u;
    unsigned r = u >> 16;
    unsigned rem = u & 0xffffu;
    r += (rem > 0x8000u) || ((rem == 0x8000u) && (r & 1u));
    return (unsigned short)r;
}
__device__ __forceinline__ float bf2f(unsigned short h) {
    union { unsigned u; float f; } c; c.u = ((unsigned)h) << 16;
    return c.f;
}

// ---------------- elementwise conversion kernels ----------------

__global__ void split_kernel(const float* __restrict__ in,
                             unsigned short* __restrict__ hi,
                             unsigned short* __restrict__ lo, int n) {
    int i = blockIdx.x * blockDim.x + threadIdx.x;
    if (i >= n) return;
    float f = in[i];
    unsigned short h = f2bf(f);
    hi[i] = h;
    lo[i] = f2bf(f - bf2f(h));
}

__global__ void cvt_kernel(const float* __restrict__ in,
                           unsigned short* __restrict__ out, int n) {
    int i = blockIdx.x * blockDim.x + threadIdx.x;
    if (i >= n) return;
    out[i] = f2bf(in[i]);
}

// ---------------- MFMA GEMM (C = A * B^T + bias), bf16 inputs ----------------

__device__ __forceinline__ void gld16(const unsigned short* g, unsigned short* l) {
    __builtin_amdgcn_global_load_lds(
        (const __attribute__((address_space(1))) unsigned int*)g,
        (__attribute__((address_space(3))) unsigned int*)l, 16, 0, 0);
}

template <bool SPLIT>
__global__ __launch_bounds__(256)
void gemm_bt(const unsigned short* __restrict__ Ah, const unsigned short* __restrict__ Al,
             const unsigned short* __restrict__ Bh, const unsigned short* __restrict__ Bl,
             const float* __restrict__ bias, float* __restrict__ C,
             int M, int N, int K) {
    constexpr int BM = 128, BN = 128, BK = 32;
    extern __shared__ unsigned short smem[];
    unsigned short* sAh = smem;             // BM*BK = 4096 elements
    unsigned short* sBh = smem + 4096;
    unsigned short* sAl = smem + 8192;      // used only when SPLIT
    unsigned short* sBl = smem + 12288;

    const int tid  = threadIdx.x;
    const int lane = tid & 63;
    const int wid  = tid >> 6;
    const int wr   = wid >> 1, wc = wid & 1;
    const int m16  = lane & 15, quad = lane >> 4;

    const int rowA0 = blockIdx.y * BM;
    const int rowB0 = blockIdx.x * BN;

    floatx4 acc[4][4];
#pragma unroll
    for (int i = 0; i < 4; i++)
#pragma unroll
        for (int j = 0; j < 4; j++) acc[i][j] = (floatx4){0.f, 0.f, 0.f, 0.f};

    const int nk = K / BK;
    for (int kt = 0; kt < nk; ++kt) {
        const int k0 = kt * BK;
#pragma unroll
        for (int i = 0; i < 2; i++) {
            int c  = tid + 256 * i;       // 0..511 chunk id; 16B per chunk
            int r  = c >> 2;              // tile row 0..127
            int cc = c & 3;               // 16B column chunk within row
            gld16(Ah + (size_t)(rowA0 + r) * K + k0 + cc * 8, sAh + c * 8);
            gld16(Bh + (size_t)(rowB0 + r) * K + k0 + cc * 8, sBh + c * 8);
            if (SPLIT) {
                gld16(Al + (size_t)(rowA0 + r) * K + k0 + cc * 8, sAl + c * 8);
                gld16(Bl + (size_t)(rowB0 + r) * K + k0 + cc * 8, sBl + c * 8);
            }
        }
        __syncthreads();

        short8 a[4], b[4], al[4], bl[4];
#pragma unroll
        for (int i = 0; i < 4; i++) {
            a[i] = *(const short8*)(sAh + (wr * 64 + i * 16 + m16) * BK + quad * 8);
            b[i] = *(const short8*)(sBh + (wc * 64 + i * 16 + m16) * BK + quad * 8);
            if (SPLIT) {
                al[i] = *(const short8*)(sAl + (wr * 64 + i * 16 + m16) * BK + quad * 8);
                bl[i] = *(const short8*)(sBl + (wc * 64 + i * 16 + m16) * BK + quad * 8);
            }
        }
#pragma unroll
        for (int i = 0; i < 4; i++)
#pragma unroll
            for (int j = 0; j < 4; j++) {
                acc[i][j] = __builtin_amdgcn_mfma_f32_16x16x32_bf16(a[i], b[j], acc[i][j], 0, 0, 0);
                if (SPLIT) {
                    acc[i][j] = __builtin_amdgcn_mfma_f32_16x16x32_bf16(a[i], bl[j], acc[i][j], 0, 0, 0);
                    acc[i][j] = __builtin_amdgcn_mfma_f32_16x16x32_bf16(al[i], b[j], acc[i][j], 0, 0, 0);
                }
            }
        __syncthreads();
    }

#pragma unroll
    for (int i = 0; i < 4; i++) {
#pragma unroll
        for (int j = 0; j < 4; j++) {
            int col  = rowB0 + wc * 64 + j * 16 + m16;
            float bv = bias[col];
#pragma unroll
            for (int r = 0; r < 4; r++) {
                int row = rowA0 + wr * 64 + i * 16 + quad * 4 + r;
                C[(size_t)row * N + col] = acc[i][j][r] + bv;
            }
        }
    }
}

// ---------------- parallel quaternion prefix-product scan ----------------
// Since |q|=1 for each input quat, normalize(q_t * normalize(...)) equals
// normalize(q_t * ... * q_0) up to O(S*1e-8) in magnitude. So the recurrence
// is an associative prefix product -> Hillis-Steele scan.
// Block = one (b,h) chain, 256 threads x 8 steps each.

struct Q { float w, x, y, z; };

__device__ __forceinline__ Q qmul(Q a, Q b) {   // a later (left), b earlier
    Q r;
    r.w = a.w * b.w - a.x * b.x - a.y * b.y - a.z * b.z;
    r.x = a.w * b.x + a.x * b.w + a.y * b.z - a.z * b.y;
    r.y = a.w * b.y - a.x * b.z + a.y * b.w + a.z * b.x;
    r.z = a.w * b.z + a.x * b.y - a.y * b.x + a.z * b.w;
    return r;
}
__device__ __forceinline__ Q qnorm(Q a) {
    float nn = a.w * a.w + a.x * a.x + a.y * a.y + a.z * a.z;
    float inv = __frsqrt_rn(nn);
    Q r; r.w = a.w * inv; r.x = a.x * inv; r.y = a.y * inv; r.z = a.z * inv;
    return r;
}

__global__ __launch_bounds__(256)
void scan_kernel(const float* __restrict__ v, unsigned short* __restrict__ st,
                 float* __restrict__ m_final, int S, int H) {
    const int chain = blockIdx.x;        // b*H + h
    const int b = chain >> 10;           // H == 1024
    const int h = chain & 1023;
    const int tid = threadIdx.x;
    const int lane = tid & 63, wv = tid >> 6;

    const size_t vstep = (size_t)3 * H;
    const float* vp = v + ((size_t)b * S) * vstep + (size_t)h * 3;

    const int s0 = tid * 8;

    // 1) local segment: 8 sequential quat products
    Q R[8];
    Q c = {1.f, 0.f, 0.f, 0.f};
#pragma unroll
    for (int k = 0; k < 8; k++) {
        const float* p = vp + (size_t)(s0 + k) * vstep;
        float vx = p[0], vy = p[1], vz = p[2];
        float th = sqrtf(vx * vx + vy * vy + vz * vz);
        float s_, c_;
        __sincosf(th, &s_, &c_);
        float kk = __fdividef(s_, th + EPSF);
        Q q; q.w = c_; q.x = kk * vx; q.y = kk * vy; q.z = kk * vz;
        c = qmul(q, c);
        R[k] = c;
    }
    Q L = qnorm(c);

    // 2) wave-level inclusive scan (non-commutative: later * earlier)
    Q I = L;
#pragma unroll
    for (int d = 1; d < 64; d <<= 1) {
        Q y;
        y.w = __shfl_up(I.w, d);
        y.x = __shfl_up(I.x, d);
        y.y = __shfl_up(I.y, d);
        y.z = __shfl_up(I.z, d);
        if (lane >= d) I = qmul(I, y);
    }

    // 3) cross-wave combine via LDS
    __shared__ float wq[4][4];
    if (lane == 63) { wq[wv][0] = I.w; wq[wv][1] = I.x; wq[wv][2] = I.y; wq[wv][3] = I.z; }
    __syncthreads();
    Q W = {1.f, 0.f, 0.f, 0.f};
    for (int j = 0; j < wv; j++) {
        Q t; t.w = wq[j][0]; t.x = wq[j][1]; t.y = wq[j][2]; t.z = wq[j][3];
        W = qmul(t, W);     // t covers later indices than accumulated W
    }

    // exclusive prefix for this thread: E = (within-wave excl) * (wave prefix)
    Q e;
    e.w = __shfl_up(I.w, 1);
    e.x = __shfl_up(I.x, 1);
    e.y = __shfl_up(I.y, 1);
    e.z = __shfl_up(I.z, 1);
    if (lane == 0) { e.w = 1.f; e.x = 0.f; e.y = 0.f; e.z = 0.f; }
    Q E = qmul(e, W);

    // 4) apply prefix, normalize, store bf16 states
    unsigned short* sp = st + ((size_t)b * S + s0) * (size_t)(4 * H) + (size_t)h * 4;
#pragma unroll
    for (int k = 0; k < 8; k++) {
        Q m = qnorm(qmul(R[k], E));
        ushort4 u;
        u.x = f2bf(m.w); u.y = f2bf(m.x); u.z = f2bf(m.y); u.w = f2bf(m.z);
        *(ushort4*)(sp + (size_t)k * 4 * H) = u;
    }

    if (tid == 255) {
        Q m = qnorm(qmul(R[7], E));
        float* mf = m_final + (size_t)chain * 4;
        mf[0] = m.w; mf[1] = m.x; mf[2] = m.y; mf[3] = m.z;
    }
}

// ---------------- launch ----------------

extern "C" void kernel_launch(void* const* d_in, const int* in_sizes, int n_in,
                              void* d_out, int out_size, void* d_ws, size_t ws_size,
                              hipStream_t stream) {
    const float* x     = (const float*)d_in[0];
    const float* W_in  = (const float*)d_in[1];
    const float* b_in  = (const float*)d_in[2];
    const float* W_out = (const float*)d_in[3];
    const float* b_out = (const float*)d_in[4];
    float* out = (float*)d_out;

    const int B = 4, S = 2048, D = 1024, H = 1024;
    const int M  = B * S;    // 8192
    const int N1 = 3 * H;    // 3072
    const int K1 = D;        // 1024
    const int N2 = D;        // 1024
    const int K2 = 4 * H;    // 4096

    char* ws = (char*)d_ws;
    float*          v   = (float*)(ws);
    unsigned short* st  = (unsigned short*)(ws + 100663296u);
    unsigned short* woh = (unsigned short*)(ws + 167772160u);
    unsigned short* xh  = (unsigned short*)(ws + 100663296u);
    unsigned short* xl  = (unsigned short*)(ws + 100663296u + 16777216u);
    unsigned short* wih = (unsigned short*)(ws + 100663296u + 33554432u);
    unsigned short* wil = (unsigned short*)(ws + 100663296u + 33554432u + 6291456u);

    const int nx  = M * K1;    // 8388608
    const int nw  = N1 * K1;   // 3145728
    const int nwo = N2 * K2;   // 4194304

    split_kernel<<<(nx + 255) / 256, 256, 0, stream>>>(x, xh, xl, nx);
    split_kernel<<<(nw + 255) / 256, 256, 0, stream>>>(W_in, wih, wil, nw);
    cvt_kernel<<<(nwo + 255) / 256, 256, 0, stream>>>(W_out, woh, nwo);

    // v = x @ W_in^T + b_in   (split-bf16, fp32-accurate)
    gemm_bt<true><<<dim3(N1 / 128, M / 128), 256, 32768, stream>>>(
        xh, xl, wih, wil, b_in, v, M, N1, K1);

    // parallel prefix-product scan; writes states (bf16) + m_final (fp32)
    scan_kernel<<<B * H, 256, 0, stream>>>(v, st, out + (size_t)M * D, S, H);

    // out = states @ W_out^T + b_out
    gemm_bt<false><<<dim3(N2 / 128, M / 128), 256, 16384, stream>>>(
        st, nullptr, woh, nullptr, b_out, out, M, N2, K2);
}

// Round 3
// 450.900 us; speedup vs baseline: 2.0098x; 1.4546x over previous
//
#include <hip/hip_runtime.h>
#include <hip/hip_bf16.h>
#include <stdint.h>

#define EPSF 1e-8f

typedef __attribute__((ext_vector_type(8))) short short8;
typedef __attribute__((ext_vector_type(4))) float floatx4;

__device__ __forceinline__ unsigned short f2bf(float f) {
    union { float f; unsigned u; } c; c.f = f;
    unsigned u = c.u;
    unsigned r = u >> 16;
    unsigned rem = u & 0xffffu;
    r += (rem > 0x8000u) || ((rem == 0x8000u) && (r & 1u));
    return (unsigned short)r;
}
__device__ __forceinline__ float bf2f(unsigned short h) {
    union { unsigned u; float f; } c; c.u = ((unsigned)h) << 16;
    return c.f;
}

// ---------------- elementwise conversion kernels ----------------

__global__ void split_kernel(const float* __restrict__ in,
                             unsigned short* __restrict__ hi,
                             unsigned short* __restrict__ lo, int n) {
    int i = blockIdx.x * blockDim.x + threadIdx.x;
    if (i >= n) return;
    float f = in[i];
    unsigned short h = f2bf(f);
    hi[i] = h;
    lo[i] = f2bf(f - bf2f(h));
}

__global__ void cvt_kernel(const float* __restrict__ in,
                           unsigned short* __restrict__ out, int n) {
    int i = blockIdx.x * blockDim.x + threadIdx.x;
    if (i >= n) return;
    out[i] = f2bf(in[i]);
}

// ---------------- MFMA GEMM (C = A * B^T + bias), bf16 inputs ----------------

__device__ __forceinline__ void gld16(const unsigned short* g, unsigned short* l) {
    __builtin_amdgcn_global_load_lds(
        (const __attribute__((address_space(1))) unsigned int*)g,
        (__attribute__((address_space(3))) unsigned int*)l, 16, 0, 0);
}

template <bool SPLIT>
__global__ __launch_bounds__(256)
void gemm_bt(const unsigned short* __restrict__ Ah, const unsigned short* __restrict__ Al,
             const unsigned short* __restrict__ Bh, const unsigned short* __restrict__ Bl,
             const float* __restrict__ bias, float* __restrict__ C,
             int M, int N, int K) {
    constexpr int BM = 128, BN = 128, BK = 32;
    extern __shared__ unsigned short smem[];
    unsigned short* sAh = smem;             // BM*BK = 4096 elements
    unsigned short* sBh = smem + 4096;
    unsigned short* sAl = smem + 8192;      // used only when SPLIT
    unsigned short* sBl = smem + 12288;

    const int tid  = threadIdx.x;
    const int lane = tid & 63;
    const int wid  = tid >> 6;
    const int wr   = wid >> 1, wc = wid & 1;
    const int m16  = lane & 15, quad = lane >> 4;

    const int rowA0 = blockIdx.y * BM;
    const int rowB0 = blockIdx.x * BN;

    floatx4 acc[4][4];
#pragma unroll
    for (int i = 0; i < 4; i++)
#pragma unroll
        for (int j = 0; j < 4; j++) acc[i][j] = (floatx4){0.f, 0.f, 0.f, 0.f};

    const int nk = K / BK;
    for (int kt = 0; kt < nk; ++kt) {
        const int k0 = kt * BK;
#pragma unroll
        for (int i = 0; i < 2; i++) {
            int c  = tid + 256 * i;       // 0..511 chunk id; 16B per chunk
            int r  = c >> 2;              // tile row 0..127
            int cc = c & 3;               // 16B column chunk within row
            gld16(Ah + (size_t)(rowA0 + r) * K + k0 + cc * 8, sAh + c * 8);
            gld16(Bh + (size_t)(rowB0 + r) * K + k0 + cc * 8, sBh + c * 8);
            if (SPLIT) {
                gld16(Al + (size_t)(rowA0 + r) * K + k0 + cc * 8, sAl + c * 8);
                gld16(Bl + (size_t)(rowB0 + r) * K + k0 + cc * 8, sBl + c * 8);
            }
        }
        __syncthreads();

        short8 a[4], b[4], al[4], bl[4];
#pragma unroll
        for (int i = 0; i < 4; i++) {
            a[i] = *(const short8*)(sAh + (wr * 64 + i * 16 + m16) * BK + quad * 8);
            b[i] = *(const short8*)(sBh + (wc * 64 + i * 16 + m16) * BK + quad * 8);
            if (SPLIT) {
                al[i] = *(const short8*)(sAl + (wr * 64 + i * 16 + m16) * BK + quad * 8);
                bl[i] = *(const short8*)(sBl + (wc * 64 + i * 16 + m16) * BK + quad * 8);
            }
        }
#pragma unroll
        for (int i = 0; i < 4; i++)
#pragma unroll
            for (int j = 0; j < 4; j++) {
                acc[i][j] = __builtin_amdgcn_mfma_f32_16x16x32_bf16(a[i], b[j], acc[i][j], 0, 0, 0);
                if (SPLIT) {
                    acc[i][j] = __builtin_amdgcn_mfma_f32_16x16x32_bf16(a[i], bl[j], acc[i][j], 0, 0, 0);
                    acc[i][j] = __builtin_amdgcn_mfma_f32_16x16x32_bf16(al[i], b[j], acc[i][j], 0, 0, 0);
                }
            }
        __syncthreads();
    }

#pragma unroll
    for (int i = 0; i < 4; i++) {
#pragma unroll
        for (int j = 0; j < 4; j++) {
            int col  = rowB0 + wc * 64 + j * 16 + m16;
            float bv = bias[col];
#pragma unroll
            for (int r = 0; r < 4; r++) {
                int row = rowA0 + wr * 64 + i * 16 + quad * 4 + r;
                C[(size_t)row * N + col] = acc[i][j][r] + bv;
            }
        }
    }
}

// ---------------- hierarchical quaternion prefix-product scan ----------------
// Unit-norm inputs: normalize-every-step == one final normalize (magnitude
// drift O(S*1e-8)). So states = qnorm(prefix products). 3-phase scan with
// fully coalesced v reads (wave = 64 consecutive h, same s -> 768 B/instr)
// and coalesced bf16 state writes (512 B/instr).
//
// SEG = 64 steps, NSEG = 32 segments.
// K1: partials[b][seg][h] = product of quats in segment (raw fp32)
// K2: in-place exclusive scan of partials over seg, per chain; emits m_final
// K3: re-read v, apply prefix, normalize, write bf16 states

struct Q { float w, x, y, z; };

__device__ __forceinline__ Q qmul(Q a, Q b) {   // a later (left), b earlier
    Q r;
    r.w = a.w * b.w - a.x * b.x - a.y * b.y - a.z * b.z;
    r.x = a.w * b.x + a.x * b.w + a.y * b.z - a.z * b.y;
    r.y = a.w * b.y - a.x * b.z + a.y * b.w + a.z * b.x;
    r.z = a.w * b.z + a.x * b.y - a.y * b.x + a.z * b.w;
    return r;
}
__device__ __forceinline__ Q qnorm(Q a) {
    float nn = a.w * a.w + a.x * a.x + a.y * a.y + a.z * a.z;
    float inv = __frsqrt_rn(nn);
    Q r; r.w = a.w * inv; r.x = a.x * inv; r.y = a.y * inv; r.z = a.z * inv;
    return r;
}
__device__ __forceinline__ Q vquat(float vx, float vy, float vz) {
    float th = sqrtf(vx * vx + vy * vy + vz * vz);
    float s_, c_;
    __sincosf(th, &s_, &c_);
    float k = __fdividef(s_, th + EPSF);
    Q q; q.w = c_; q.x = k * vx; q.y = k * vy; q.z = k * vz;
    return q;
}

#define SEG  64
#define NSEG 32

// block: 256 thr = 64 h x 4 segments; grid (NSEG/4, H/64, B)
__global__ __launch_bounds__(256)
void seg_prod_kernel(const float* __restrict__ v, float* __restrict__ partials,
                     int S, int H) {
    const int b  = blockIdx.z;
    const int h  = blockIdx.y * 64 + (threadIdx.x & 63);
    const int sg = blockIdx.x * 4 + (threadIdx.x >> 6);
    const int s0 = sg * SEG;
    const size_t vstep = (size_t)3 * H;
    const float* vp = v + ((size_t)b * S + s0) * vstep + (size_t)h * 3;

    constexpr int CH = 8;
    float ax[CH], ay[CH], az[CH], bx[CH], by[CH], bz[CH];
#pragma unroll
    for (int i = 0; i < CH; ++i) {
        ax[i] = vp[i * vstep + 0]; ay[i] = vp[i * vstep + 1]; az[i] = vp[i * vstep + 2];
    }
    Q c = {1.f, 0.f, 0.f, 0.f};
    const int NC = SEG / CH;  // 8 chunks
    for (int cc = 0; cc < NC; cc += 2) {
        if (cc + 1 < NC) {
            const float* p = vp + (size_t)(cc + 1) * CH * vstep;
#pragma unroll
            for (int i = 0; i < CH; ++i) {
                bx[i] = p[i * vstep + 0]; by[i] = p[i * vstep + 1]; bz[i] = p[i * vstep + 2];
            }
        }
#pragma unroll
        for (int i = 0; i < CH; ++i) c = qmul(vquat(ax[i], ay[i], az[i]), c);
        if (cc + 2 < NC) {
            const float* p = vp + (size_t)(cc + 2) * CH * vstep;
#pragma unroll
            for (int i = 0; i < CH; ++i) {
                ax[i] = p[i * vstep + 0]; ay[i] = p[i * vstep + 1]; az[i] = p[i * vstep + 2];
            }
        }
#pragma unroll
        for (int i = 0; i < CH; ++i) c = qmul(vquat(bx[i], by[i], bz[i]), c);
    }
    float4* dst = (float4*)(partials + (((size_t)b * NSEG + sg) * H + h) * 4);
    *dst = make_float4(c.w, c.x, c.y, c.z);
}

// 4096 threads, one per chain; in-place exclusive scan over NSEG segments.
__global__ __launch_bounds__(256)
void seg_scan_kernel(float* __restrict__ partials, float* __restrict__ m_final, int H) {
    const int t = blockIdx.x * blockDim.x + threadIdx.x;  // b*H + h
    const int b = t >> 10, h = t & 1023;
    Q r = {1.f, 0.f, 0.f, 0.f};
    for (int sg = 0; sg < NSEG; ++sg) {
        float4* p = (float4*)(partials + (((size_t)b * NSEG + sg) * H + h) * 4);
        float4 pv = *p;
        *p = make_float4(r.w, r.x, r.y, r.z);   // exclusive prefix
        Q pq = {pv.x, pv.y, pv.z, pv.w};
        r = qmul(pq, r);
    }
    r = qnorm(r);
    float* mf = m_final + (size_t)t * 4;
    mf[0] = r.w; mf[1] = r.x; mf[2] = r.y; mf[3] = r.z;
}

// same mapping as K1; applies prefix, writes bf16 states coalesced.
__global__ __launch_bounds__(256)
void apply_kernel(const float* __restrict__ v, const float* __restrict__ pfx,
                  unsigned short* __restrict__ st, int S, int H) {
    const int b  = blockIdx.z;
    const int h  = blockIdx.y * 64 + (threadIdx.x & 63);
    const int sg = blockIdx.x * 4 + (threadIdx.x >> 6);
    const int s0 = sg * SEG;
    const size_t vstep = (size_t)3 * H;
    const size_t sstep = (size_t)4 * H;
    const float* vp = v + ((size_t)b * S + s0) * vstep + (size_t)h * 3;
    unsigned short* sp = st + ((size_t)b * S + s0) * sstep + (size_t)h * 4;

    float4 p = *(const float4*)(pfx + (((size_t)b * NSEG + sg) * H + h) * 4);
    Q R = {p.x, p.y, p.z, p.w};

    constexpr int CH = 8;
    float ax[CH], ay[CH], az[CH], bx[CH], by[CH], bz[CH];
#pragma unroll
    for (int i = 0; i < CH; ++i) {
        ax[i] = vp[i * vstep + 0]; ay[i] = vp[i * vstep + 1]; az[i] = vp[i * vstep + 2];
    }
    const int NC = SEG / CH;
    for (int cc = 0; cc < NC; cc += 2) {
        if (cc + 1 < NC) {
            const float* pp = vp + (size_t)(cc + 1) * CH * vstep;
#pragma unroll
            for (int i = 0; i < CH; ++i) {
                bx[i] = pp[i * vstep + 0]; by[i] = pp[i * vstep + 1]; bz[i] = pp[i * vstep + 2];
            }
        }
#pragma unroll
        for (int i = 0; i < CH; ++i) {
            R = qmul(vquat(ax[i], ay[i], az[i]), R);
            Q m = qnorm(R);
            ushort4 u; u.x = f2bf(m.w); u.y = f2bf(m.x); u.z = f2bf(m.y); u.w = f2bf(m.z);
            *(ushort4*)(sp + (size_t)(cc * CH + i) * sstep) = u;
        }
        if (cc + 2 < NC) {
            const float* pp = vp + (size_t)(cc + 2) * CH * vstep;
#pragma unroll
            for (int i = 0; i < CH; ++i) {
                ax[i] = pp[i * vstep + 0]; ay[i] = pp[i * vstep + 1]; az[i] = pp[i * vstep + 2];
            }
        }
#pragma unroll
        for (int i = 0; i < CH; ++i) {
            R = qmul(vquat(bx[i], by[i], bz[i]), R);
            Q m = qnorm(R);
            ushort4 u; u.x = f2bf(m.w); u.y = f2bf(m.x); u.z = f2bf(m.y); u.w = f2bf(m.z);
            *(ushort4*)(sp + (size_t)((cc + 1) * CH + i) * sstep) = u;
        }
    }
}

// ---------------- launch ----------------

extern "C" void kernel_launch(void* const* d_in, const int* in_sizes, int n_in,
                              void* d_out, int out_size, void* d_ws, size_t ws_size,
                              hipStream_t stream) {
    const float* x     = (const float*)d_in[0];
    const float* W_in  = (const float*)d_in[1];
    const float* b_in  = (const float*)d_in[2];
    const float* W_out = (const float*)d_in[3];
    const float* b_out = (const float*)d_in[4];
    float* out = (float*)d_out;

    const int B = 4, S = 2048, D = 1024, H = 1024;
    const int M  = B * S;    // 8192
    const int N1 = 3 * H;    // 3072
    const int K1 = D;        // 1024
    const int N2 = D;        // 1024
    const int K2 = 4 * H;    // 4096

    char* ws = (char*)d_ws;
    float*          v   = (float*)(ws);
    unsigned short* st  = (unsigned short*)(ws + 100663296u);
    unsigned short* woh = (unsigned short*)(ws + 167772160u);
    unsigned short* xh  = (unsigned short*)(ws + 100663296u);
    unsigned short* xl  = (unsigned short*)(ws + 100663296u + 16777216u);
    unsigned short* wih = (unsigned short*)(ws + 100663296u + 33554432u);
    unsigned short* wil = (unsigned short*)(ws + 100663296u + 33554432u + 6291456u);

    // partials (2 MB) live in d_out — free until GEMM2 overwrites it last.
    float* partials = out;

    const int nx  = M * K1;    // 8388608
    const int nw  = N1 * K1;   // 3145728
    const int nwo = N2 * K2;   // 4194304

    split_kernel<<<(nx + 255) / 256, 256, 0, stream>>>(x, xh, xl, nx);
    split_kernel<<<(nw + 255) / 256, 256, 0, stream>>>(W_in, wih, wil, nw);
    cvt_kernel<<<(nwo + 255) / 256, 256, 0, stream>>>(W_out, woh, nwo);

    // v = x @ W_in^T + b_in   (split-bf16, fp32-accurate)
    gemm_bt<true><<<dim3(N1 / 128, M / 128), 256, 32768, stream>>>(
        xh, xl, wih, wil, b_in, v, M, N1, K1);

    // hierarchical scan
    dim3 sg_grid(NSEG / 4, H / 64, B);
    seg_prod_kernel<<<sg_grid, 256, 0, stream>>>(v, partials, S, H);
    seg_scan_kernel<<<(B * H) / 256, 256, 0, stream>>>(partials, out + (size_t)M * D, H);
    apply_kernel<<<sg_grid, 256, 0, stream>>>(v, partials, st, S, H);

    // out = states @ W_out^T + b_out
    gemm_bt<false><<<dim3(N2 / 128, M / 128), 256, 16384, stream>>>(
        st, nullptr, woh, nullptr, b_out, out, M, N2, K2);
}

// Round 4
// 419.570 us; speedup vs baseline: 2.1599x; 1.0747x over previous
//
#include <hip/hip_runtime.h>
#include <hip/hip_bf16.h>
#include <stdint.h>

#define EPSF 1e-8f

typedef __attribute__((ext_vector_type(8))) short short8;
typedef __attribute__((ext_vector_type(4))) float floatx4;

__device__ __forceinline__ unsigned short f2bf(float f) {
    union { float f; unsigned u; } c; c.f = f;
    unsigned u = c.u;
    unsigned r = u >> 16;
    unsigned rem = u & 0xffffu;
    r += (rem > 0x8000u) || ((rem == 0x8000u) && (r & 1u));
    return (unsigned short)r;
}
__device__ __forceinline__ float bf2f(unsigned short h) {
    union { unsigned u; float f; } c; c.u = ((unsigned)h) << 16;
    return c.f;
}

// ---------------- fused conversion kernel ----------------
// job 0: split x -> xh, xl   job 1: split W_in -> wih, wil   job 2: cvt W_out

__global__ void prep_kernel(const float* __restrict__ x,
                            unsigned short* __restrict__ xh, unsigned short* __restrict__ xl,
                            const float* __restrict__ wi,
                            unsigned short* __restrict__ wih, unsigned short* __restrict__ wil,
                            const float* __restrict__ wo, unsigned short* __restrict__ woh,
                            int nx, int nw, int nwo) {
    int i = blockIdx.x * blockDim.x + threadIdx.x;
    if (i < nx) {
        float f = x[i];
        unsigned short h = f2bf(f);
        xh[i] = h; xl[i] = f2bf(f - bf2f(h));
    } else if (i < nx + nw) {
        int j = i - nx;
        float f = wi[j];
        unsigned short h = f2bf(f);
        wih[j] = h; wil[j] = f2bf(f - bf2f(h));
    } else if (i < nx + nw + nwo) {
        int j = i - nx - nw;
        woh[j] = f2bf(wo[j]);
    }
}

// ---------------- MFMA GEMM (C = A * B^T + bias), bf16 inputs ----------------
// XOR-swizzled LDS chunk layout: global chunk (r, cc^(r&(CPR-1))) is stored at
// LDS slot r*CPR+cc (global_load_lds forces slot = lane order; we choose the
// source). Spreads fragment ds_read_b128 rows across bank groups.

__device__ __forceinline__ void gld16(const unsigned short* g, unsigned short* l) {
    __builtin_amdgcn_global_load_lds(
        (const __attribute__((address_space(1))) unsigned int*)g,
        (__attribute__((address_space(3))) unsigned int*)l, 16, 0, 0);
}

template <bool SPLIT, int BK>
__global__ __launch_bounds__(256)
void gemm_bt(const unsigned short* __restrict__ Ah, const unsigned short* __restrict__ Al,
             const unsigned short* __restrict__ Bh, const unsigned short* __restrict__ Bl,
             const float* __restrict__ bias, float* __restrict__ C,
             int M, int N, int K) {
    constexpr int BM = 128, BN = 128;
    constexpr int CPR = BK / 8;        // 16B chunks per row
    constexpr int NCH = BM * CPR;      // chunks per buffer
    constexpr int PC  = NCH / 256;     // chunks per thread per buffer
    constexpr int KH  = BK / 32;       // mfma k-steps per tile
    extern __shared__ unsigned short smem[];
    unsigned short* sAh = smem;
    unsigned short* sBh = smem + BM * BK;
    unsigned short* sAl = smem + 2 * BM * BK;   // only when SPLIT
    unsigned short* sBl = smem + 3 * BM * BK;

    const int tid  = threadIdx.x;
    const int lane = tid & 63;
    const int wid  = tid >> 6;
    const int wr   = wid >> 1, wc = wid & 1;
    const int m16  = lane & 15, quad = lane >> 4;

    const int rowA0 = blockIdx.y * BM;
    const int rowB0 = blockIdx.x * BN;

    floatx4 acc[4][4];
#pragma unroll
    for (int i = 0; i < 4; i++)
#pragma unroll
        for (int j = 0; j < 4; j++) acc[i][j] = (floatx4){0.f, 0.f, 0.f, 0.f};

    const int nk = K / BK;
    for (int kt = 0; kt < nk; ++kt) {
        const int k0 = kt * BK;
#pragma unroll
        for (int i = 0; i < PC; i++) {
            int c   = tid + 256 * i;
            int r   = c / CPR;
            int ccl = c & (CPR - 1);
            int ccg = ccl ^ (r & (CPR - 1));   // swizzled global chunk
            gld16(Ah + (size_t)(rowA0 + r) * K + k0 + ccg * 8, sAh + c * 8);
            gld16(Bh + (size_t)(rowB0 + r) * K + k0 + ccg * 8, sBh + c * 8);
            if (SPLIT) {
                gld16(Al + (size_t)(rowA0 + r) * K + k0 + ccg * 8, sAl + c * 8);
                gld16(Bl + (size_t)(rowB0 + r) * K + k0 + ccg * 8, sBl + c * 8);
            }
        }
        __syncthreads();

        short8 a[KH][4], b[KH][4], al[KH][4], bl[KH][4];
#pragma unroll
        for (int kh = 0; kh < KH; kh++) {
#pragma unroll
            for (int i = 0; i < 4; i++) {
                int ra = wr * 64 + i * 16 + m16;
                int rb = wc * 64 + i * 16 + m16;
                int kc = kh * 4 + quad;
                int pa = ra * CPR + (kc ^ (ra & (CPR - 1)));
                int pb = rb * CPR + (kc ^ (rb & (CPR - 1)));
                a[kh][i] = *(const short8*)(sAh + pa * 8);
                b[kh][i] = *(const short8*)(sBh + pb * 8);
                if (SPLIT) {
                    al[kh][i] = *(const short8*)(sAl + pa * 8);
                    bl[kh][i] = *(const short8*)(sBl + pb * 8);
                }
            }
        }
#pragma unroll
        for (int kh = 0; kh < KH; kh++)
#pragma unroll
            for (int i = 0; i < 4; i++)
#pragma unroll
                for (int j = 0; j < 4; j++) {
                    acc[i][j] = __builtin_amdgcn_mfma_f32_16x16x32_bf16(a[kh][i], b[kh][j], acc[i][j], 0, 0, 0);
                    if (SPLIT) {
                        acc[i][j] = __builtin_amdgcn_mfma_f32_16x16x32_bf16(a[kh][i], bl[kh][j], acc[i][j], 0, 0, 0);
                        acc[i][j] = __builtin_amdgcn_mfma_f32_16x16x32_bf16(al[kh][i], b[kh][j], acc[i][j], 0, 0, 0);
                    }
                }
        __syncthreads();
    }

#pragma unroll
    for (int i = 0; i < 4; i++) {
#pragma unroll
        for (int j = 0; j < 4; j++) {
            int col  = rowB0 + wc * 64 + j * 16 + m16;
            float bv = bias[col];
#pragma unroll
            for (int r = 0; r < 4; r++) {
                int row = rowA0 + wr * 64 + i * 16 + quad * 4 + r;
                C[(size_t)row * N + col] = acc[i][j][r] + bv;
            }
        }
    }
}

// ---------------- hierarchical quaternion prefix-product scan ----------------

struct Q { float w, x, y, z; };

__device__ __forceinline__ Q qmul(Q a, Q b) {   // a later (left), b earlier
    Q r;
    r.w = a.w * b.w - a.x * b.x - a.y * b.y - a.z * b.z;
    r.x = a.w * b.x + a.x * b.w + a.y * b.z - a.z * b.y;
    r.y = a.w * b.y - a.x * b.z + a.y * b.w + a.z * b.x;
    r.z = a.w * b.z + a.x * b.y - a.y * b.x + a.z * b.w;
    return r;
}
__device__ __forceinline__ Q qnorm(Q a) {
    float nn = a.w * a.w + a.x * a.x + a.y * a.y + a.z * a.z;
    float inv = __frsqrt_rn(nn);
    Q r; r.w = a.w * inv; r.x = a.x * inv; r.y = a.y * inv; r.z = a.z * inv;
    return r;
}
__device__ __forceinline__ Q vquat(float vx, float vy, float vz) {
    float th = sqrtf(vx * vx + vy * vy + vz * vz);
    float s_, c_;
    __sincosf(th, &s_, &c_);
    float k = __fdividef(s_, th + EPSF);
    Q q; q.w = c_; q.x = k * vx; q.y = k * vy; q.z = k * vz;
    return q;
}

#define SEG  64
#define NSEG 32

// block: 256 thr = 64 h x 4 segments; grid (NSEG/4, H/64, B)
__global__ __launch_bounds__(256)
void seg_prod_kernel(const float* __restrict__ v, float* __restrict__ partials,
                     int S, int H) {
    const int b  = blockIdx.z;
    const int h  = blockIdx.y * 64 + (threadIdx.x & 63);
    const int sg = blockIdx.x * 4 + (threadIdx.x >> 6);
    const int s0 = sg * SEG;
    const size_t vstep = (size_t)3 * H;
    const float* vp = v + ((size_t)b * S + s0) * vstep + (size_t)h * 3;

    constexpr int CH = 8;
    float ax[CH], ay[CH], az[CH], bx[CH], by[CH], bz[CH];
#pragma unroll
    for (int i = 0; i < CH; ++i) {
        ax[i] = vp[i * vstep + 0]; ay[i] = vp[i * vstep + 1]; az[i] = vp[i * vstep + 2];
    }
    Q c = {1.f, 0.f, 0.f, 0.f};
    const int NC = SEG / CH;  // 8 chunks
    for (int cc = 0; cc < NC; cc += 2) {
        if (cc + 1 < NC) {
            const float* p = vp + (size_t)(cc + 1) * CH * vstep;
#pragma unroll
            for (int i = 0; i < CH; ++i) {
                bx[i] = p[i * vstep + 0]; by[i] = p[i * vstep + 1]; bz[i] = p[i * vstep + 2];
            }
        }
#pragma unroll
        for (int i = 0; i < CH; ++i) c = qmul(vquat(ax[i], ay[i], az[i]), c);
        if (cc + 2 < NC) {
            const float* p = vp + (size_t)(cc + 2) * CH * vstep;
#pragma unroll
            for (int i = 0; i < CH; ++i) {
                ax[i] = p[i * vstep + 0]; ay[i] = p[i * vstep + 1]; az[i] = p[i * vstep + 2];
            }
        }
#pragma unroll
        for (int i = 0; i < CH; ++i) c = qmul(vquat(bx[i], by[i], bz[i]), c);
    }
    float4* dst = (float4*)(partials + (((size_t)b * NSEG + sg) * H + h) * 4);
    *dst = make_float4(c.w, c.x, c.y, c.z);
}

// 4096 threads, one per chain; batch-load all segments (1 latency RT),
// then in-place exclusive scan over NSEG segments.
__global__ __launch_bounds__(256)
void seg_scan_kernel(float* __restrict__ partials, float* __restrict__ m_final, int H) {
    const int t = blockIdx.x * blockDim.x + threadIdx.x;  // b*H + h
    const int b = t >> 10, h = t & 1023;
    float4 sv[NSEG];
#pragma unroll
    for (int sg = 0; sg < NSEG; ++sg)
        sv[sg] = *(const float4*)(partials + (((size_t)b * NSEG + sg) * H + h) * 4);
    Q r = {1.f, 0.f, 0.f, 0.f};
#pragma unroll
    for (int sg = 0; sg < NSEG; ++sg) {
        *(float4*)(partials + (((size_t)b * NSEG + sg) * H + h) * 4) =
            make_float4(r.w, r.x, r.y, r.z);   // exclusive prefix
        Q pq = {sv[sg].x, sv[sg].y, sv[sg].z, sv[sg].w};
        r = qmul(pq, r);
    }
    r = qnorm(r);
    float* mf = m_final + (size_t)t * 4;
    mf[0] = r.w; mf[1] = r.x; mf[2] = r.y; mf[3] = r.z;
}

// same mapping as seg_prod; applies prefix, writes bf16 states coalesced.
__global__ __launch_bounds__(256)
void apply_kernel(const float* __restrict__ v, const float* __restrict__ pfx,
                  unsigned short* __restrict__ st, int S, int H) {
    const int b  = blockIdx.z;
    const int h  = blockIdx.y * 64 + (threadIdx.x & 63);
    const int sg = blockIdx.x * 4 + (threadIdx.x >> 6);
    const int s0 = sg * SEG;
    const size_t vstep = (size_t)3 * H;
    const size_t sstep = (size_t)4 * H;
    const float* vp = v + ((size_t)b * S + s0) * vstep + (size_t)h * 3;
    unsigned short* sp = st + ((size_t)b * S + s0) * sstep + (size_t)h * 4;

    float4 p = *(const float4*)(pfx + (((size_t)b * NSEG + sg) * H + h) * 4);
    Q R = {p.x, p.y, p.z, p.w};

    constexpr int CH = 8;
    float ax[CH], ay[CH], az[CH], bx[CH], by[CH], bz[CH];
#pragma unroll
    for (int i = 0; i < CH; ++i) {
        ax[i] = vp[i * vstep + 0]; ay[i] = vp[i * vstep + 1]; az[i] = vp[i * vstep + 2];
    }
    const int NC = SEG / CH;
    for (int cc = 0; cc < NC; cc += 2) {
        if (cc + 1 < NC) {
            const float* pp = vp + (size_t)(cc + 1) * CH * vstep;
#pragma unroll
            for (int i = 0; i < CH; ++i) {
                bx[i] = pp[i * vstep + 0]; by[i] = pp[i * vstep + 1]; bz[i] = pp[i * vstep + 2];
            }
        }
#pragma unroll
        for (int i = 0; i < CH; ++i) {
            R = qmul(vquat(ax[i], ay[i], az[i]), R);
            Q m = qnorm(R);
            ushort4 u; u.x = f2bf(m.w); u.y = f2bf(m.x); u.z = f2bf(m.y); u.w = f2bf(m.z);
            *(ushort4*)(sp + (size_t)(cc * CH + i) * sstep) = u;
        }
        if (cc + 2 < NC) {
            const float* pp = vp + (size_t)(cc + 2) * CH * vstep;
#pragma unroll
            for (int i = 0; i < CH; ++i) {
                ax[i] = pp[i * vstep + 0]; ay[i] = pp[i * vstep + 1]; az[i] = pp[i * vstep + 2];
            }
        }
#pragma unroll
        for (int i = 0; i < CH; ++i) {
            R = qmul(vquat(bx[i], by[i], bz[i]), R);
            Q m = qnorm(R);
            ushort4 u; u.x = f2bf(m.w); u.y = f2bf(m.x); u.z = f2bf(m.y); u.w = f2bf(m.z);
            *(ushort4*)(sp + (size_t)((cc + 1) * CH + i) * sstep) = u;
        }
    }
}

// ---------------- launch ----------------

extern "C" void kernel_launch(void* const* d_in, const int* in_sizes, int n_in,
                              void* d_out, int out_size, void* d_ws, size_t ws_size,
                              hipStream_t stream) {
    const float* x     = (const float*)d_in[0];
    const float* W_in  = (const float*)d_in[1];
    const float* b_in  = (const float*)d_in[2];
    const float* W_out = (const float*)d_in[3];
    const float* b_out = (const float*)d_in[4];
    float* out = (float*)d_out;

    const int B = 4, S = 2048, D = 1024, H = 1024;
    const int M  = B * S;    // 8192
    const int N1 = 3 * H;    // 3072
    const int K1 = D;        // 1024
    const int N2 = D;        // 1024
    const int K2 = 4 * H;    // 4096

    char* ws = (char*)d_ws;
    float*          v   = (float*)(ws);
    unsigned short* st  = (unsigned short*)(ws + 100663296u);
    unsigned short* woh = (unsigned short*)(ws + 167772160u);
    unsigned short* xh  = (unsigned short*)(ws + 100663296u);
    unsigned short* xl  = (unsigned short*)(ws + 100663296u + 16777216u);
    unsigned short* wih = (unsigned short*)(ws + 100663296u + 33554432u);
    unsigned short* wil = (unsigned short*)(ws + 100663296u + 33554432u + 6291456u);

    // partials (2 MB) live in d_out — free until GEMM2 overwrites it last.
    float* partials = out;

    const int nx  = M * K1;    // 8388608
    const int nw  = N1 * K1;   // 3145728
    const int nwo = N2 * K2;   // 4194304
    const int ntot = nx + nw + nwo;

    prep_kernel<<<(ntot + 255) / 256, 256, 0, stream>>>(
        x, xh, xl, W_in, wih, wil, W_out, woh, nx, nw, nwo);

    // v = x @ W_in^T + b_in   (split-bf16, fp32-accurate)
    gemm_bt<true, 32><<<dim3(N1 / 128, M / 128), 256, 32768, stream>>>(
        xh, xl, wih, wil, b_in, v, M, N1, K1);

    // hierarchical scan
    dim3 sg_grid(NSEG / 4, H / 64, B);
    seg_prod_kernel<<<sg_grid, 256, 0, stream>>>(v, partials, S, H);
    seg_scan_kernel<<<(B * H) / 256, 256, 0, stream>>>(partials, out + (size_t)M * D, H);
    apply_kernel<<<sg_grid, 256, 0, stream>>>(v, partials, st, S, H);

    // out = states @ W_out^T + b_out  (BK=64: half the barrier drains)
    gemm_bt<false, 64><<<dim3(N2 / 128, M / 128), 256, 32768, stream>>>(
        st, nullptr, woh, nullptr, b_out, out, M, N2, K2);
}

// Round 5
// 413.426 us; speedup vs baseline: 2.1920x; 1.0149x over previous
//
#include <hip/hip_runtime.h>
#include <hip/hip_bf16.h>
#include <stdint.h>

#define EPSF 1e-8f

typedef __attribute__((ext_vector_type(8))) short short8;
typedef __attribute__((ext_vector_type(8))) _Float16 half8;
typedef __attribute__((ext_vector_type(4))) float floatx4;

__device__ __forceinline__ unsigned short f2bf(float f) {
    union { float f; unsigned u; } c; c.f = f;
    unsigned u = c.u;
    unsigned r = u >> 16;
    unsigned rem = u & 0xffffu;
    r += (rem > 0x8000u) || ((rem == 0x8000u) && (r & 1u));
    return (unsigned short)r;
}
__device__ __forceinline__ unsigned short f2h(float f) {
    _Float16 h = (_Float16)f;
    return __builtin_bit_cast(unsigned short, h);
}
__device__ __forceinline__ float h2f(unsigned short u) {
    return (float)__builtin_bit_cast(_Float16, u);
}

// ---------------- fused conversion kernel ----------------
// x -> fp16 hi/lo split; W_in -> fp16; W_out -> bf16

__global__ void prep_kernel(const float* __restrict__ x,
                            unsigned short* __restrict__ xh, unsigned short* __restrict__ xl,
                            const float* __restrict__ wi, unsigned short* __restrict__ wi16,
                            const float* __restrict__ wo, unsigned short* __restrict__ woh,
                            int nx, int nw, int nwo) {
    int i = blockIdx.x * blockDim.x + threadIdx.x;
    if (i < nx) {
        float f = x[i];
        unsigned short h = f2h(f);
        xh[i] = h;
        xl[i] = f2h(f - h2f(h));
    } else if (i < nx + nw) {
        int j = i - nx;
        wi16[j] = f2h(wi[j]);
    } else if (i < nx + nw + nwo) {
        int j = i - nx - nw;
        woh[j] = f2bf(wo[j]);
    }
}

// ---------------- MFMA GEMM (C = A * B^T + bias) ----------------
// FP16: operands are fp16 bits; SPLITA: A = Ah + Al (hi/lo fp16 of fp32),
// 2 MFMAs per k-step. Otherwise plain bf16, 1 MFMA per k-step.

__device__ __forceinline__ void gld16(const unsigned short* g, unsigned short* l) {
    __builtin_amdgcn_global_load_lds(
        (const __attribute__((address_space(1))) unsigned int*)g,
        (__attribute__((address_space(3))) unsigned int*)l, 16, 0, 0);
}

template <bool FP16>
__device__ __forceinline__ floatx4 mfma16(short8 a, short8 b, floatx4 c) {
    if constexpr (FP16) {
        return __builtin_amdgcn_mfma_f32_16x16x32_f16(
            __builtin_bit_cast(half8, a), __builtin_bit_cast(half8, b), c, 0, 0, 0);
    } else {
        return __builtin_amdgcn_mfma_f32_16x16x32_bf16(a, b, c, 0, 0, 0);
    }
}

template <int BM, int BN, int BK, bool SPLITA, bool FP16>
__global__ __launch_bounds__(256)
void gemm_bt(const unsigned short* __restrict__ Ah, const unsigned short* __restrict__ Al,
             const unsigned short* __restrict__ Bm,
             const float* __restrict__ bias, float* __restrict__ C,
             int M, int N, int K) {
    constexpr int IF  = BM / 32;       // row fragments per wave (waves 2x2)
    constexpr int JF  = BN / 32;       // col fragments per wave
    constexpr int KH  = BK / 32;       // mfma k-steps per tile
    constexpr int CPR = BK / 8;        // 16B chunks per row
    extern __shared__ unsigned short smem[];
    unsigned short* sAh = smem;
    unsigned short* sAl = smem + BM * BK;                    // when SPLITA
    unsigned short* sB  = smem + (SPLITA ? 2 : 1) * BM * BK;

    const int tid  = threadIdx.x;
    const int lane = tid & 63;
    const int wid  = tid >> 6;
    const int wr   = wid >> 1, wc = wid & 1;
    const int m16  = lane & 15, quad = lane >> 4;

    const int rowA0 = blockIdx.y * BM;
    const int rowB0 = blockIdx.x * BN;

    floatx4 acc[IF][JF];
#pragma unroll
    for (int i = 0; i < IF; i++)
#pragma unroll
        for (int j = 0; j < JF; j++) acc[i][j] = (floatx4){0.f, 0.f, 0.f, 0.f};

    const int nk = K / BK;
    for (int kt = 0; kt < nk; ++kt) {
        const int k0 = kt * BK;
#pragma unroll
        for (int i = 0; i < BM * CPR / 256; i++) {
            int c = tid + 256 * i;
            int r = c / CPR, cc = c % CPR;
            gld16(Ah + (size_t)(rowA0 + r) * K + k0 + cc * 8, sAh + c * 8);
            if (SPLITA)
                gld16(Al + (size_t)(rowA0 + r) * K + k0 + cc * 8, sAl + c * 8);
        }
#pragma unroll
        for (int i = 0; i < BN * CPR / 256; i++) {
            int c = tid + 256 * i;
            int r = c / CPR, cc = c % CPR;
            gld16(Bm + (size_t)(rowB0 + r) * K + k0 + cc * 8, sB + c * 8);
        }
        __syncthreads();

        short8 a[KH][IF], al[KH][IF], b[KH][JF];
#pragma unroll
        for (int kh = 0; kh < KH; kh++) {
#pragma unroll
            for (int i = 0; i < IF; i++) {
                int ra = wr * (BM / 2) + i * 16 + m16;
                a[kh][i] = *(const short8*)(sAh + ra * BK + (kh * 4 + quad) * 8);
                if (SPLITA)
                    al[kh][i] = *(const short8*)(sAl + ra * BK + (kh * 4 + quad) * 8);
            }
#pragma unroll
            for (int j = 0; j < JF; j++) {
                int rb = wc * (BN / 2) + j * 16 + m16;
                b[kh][j] = *(const short8*)(sB + rb * BK + (kh * 4 + quad) * 8);
            }
        }
#pragma unroll
        for (int kh = 0; kh < KH; kh++)
#pragma unroll
            for (int i = 0; i < IF; i++)
#pragma unroll
                for (int j = 0; j < JF; j++) {
                    acc[i][j] = mfma16<FP16>(a[kh][i], b[kh][j], acc[i][j]);
                    if (SPLITA)
                        acc[i][j] = mfma16<FP16>(al[kh][i], b[kh][j], acc[i][j]);
                }
        __syncthreads();
    }

    // C/D layout: col=lane&15, row=quad*4+reg (verified m89/m91)
#pragma unroll
    for (int i = 0; i < IF; i++) {
#pragma unroll
        for (int j = 0; j < JF; j++) {
            int col  = rowB0 + wc * (BN / 2) + j * 16 + m16;
            float bv = bias[col];
#pragma unroll
            for (int r = 0; r < 4; r++) {
                int row = rowA0 + wr * (BM / 2) + i * 16 + quad * 4 + r;
                C[(size_t)row * N + col] = acc[i][j][r] + bv;
            }
        }
    }
}

// ---------------- hierarchical quaternion prefix-product scan ----------------

struct Q { float w, x, y, z; };

__device__ __forceinline__ Q qmul(Q a, Q b) {   // a later (left), b earlier
    Q r;
    r.w = a.w * b.w - a.x * b.x - a.y * b.y - a.z * b.z;
    r.x = a.w * b.x + a.x * b.w + a.y * b.z - a.z * b.y;
    r.y = a.w * b.y - a.x * b.z + a.y * b.w + a.z * b.x;
    r.z = a.w * b.z + a.x * b.y - a.y * b.x + a.z * b.w;
    return r;
}
__device__ __forceinline__ Q qnorm(Q a) {
    float nn = a.w * a.w + a.x * a.x + a.y * a.y + a.z * a.z;
    float inv = __frsqrt_rn(nn);
    Q r; r.w = a.w * inv; r.x = a.x * inv; r.y = a.y * inv; r.z = a.z * inv;
    return r;
}
__device__ __forceinline__ Q vquat(float vx, float vy, float vz) {
    float th = sqrtf(vx * vx + vy * vy + vz * vz);
    float s_, c_;
    __sincosf(th, &s_, &c_);
    float k = __fdividef(s_, th + EPSF);
    Q q; q.w = c_; q.x = k * vx; q.y = k * vy; q.z = k * vz;
    return q;
}

#define SEG  64
#define NSEG 32

// block: 256 thr = 64 h x 4 segments; grid (NSEG/4, H/64, B)
__global__ __launch_bounds__(256)
void seg_prod_kernel(const float* __restrict__ v, float* __restrict__ partials,
                     int S, int H) {
    const int b  = blockIdx.z;
    const int h  = blockIdx.y * 64 + (threadIdx.x & 63);
    const int sg = blockIdx.x * 4 + (threadIdx.x >> 6);
    const int s0 = sg * SEG;
    const size_t vstep = (size_t)3 * H;
    const float* vp = v + ((size_t)b * S + s0) * vstep + (size_t)h * 3;

    constexpr int CH = 8;
    float ax[CH], ay[CH], az[CH], bx[CH], by[CH], bz[CH];
#pragma unroll
    for (int i = 0; i < CH; ++i) {
        ax[i] = vp[i * vstep + 0]; ay[i] = vp[i * vstep + 1]; az[i] = vp[i * vstep + 2];
    }
    Q c = {1.f, 0.f, 0.f, 0.f};
    const int NC = SEG / CH;  // 8 chunks
    for (int cc = 0; cc < NC; cc += 2) {
        if (cc + 1 < NC) {
            const float* p = vp + (size_t)(cc + 1) * CH * vstep;
#pragma unroll
            for (int i = 0; i < CH; ++i) {
                bx[i] = p[i * vstep + 0]; by[i] = p[i * vstep + 1]; bz[i] = p[i * vstep + 2];
            }
        }
#pragma unroll
        for (int i = 0; i < CH; ++i) c = qmul(vquat(ax[i], ay[i], az[i]), c);
        if (cc + 2 < NC) {
            const float* p = vp + (size_t)(cc + 2) * CH * vstep;
#pragma unroll
            for (int i = 0; i < CH; ++i) {
                ax[i] = p[i * vstep + 0]; ay[i] = p[i * vstep + 1]; az[i] = p[i * vstep + 2];
            }
        }
#pragma unroll
        for (int i = 0; i < CH; ++i) c = qmul(vquat(bx[i], by[i], bz[i]), c);
    }
    float4* dst = (float4*)(partials + (((size_t)b * NSEG + sg) * H + h) * 4);
    *dst = make_float4(c.w, c.x, c.y, c.z);
}

// 4096 threads, one per chain; batch-load all segments, exclusive scan.
__global__ __launch_bounds__(256)
void seg_scan_kernel(float* __restrict__ partials, float* __restrict__ m_final, int H) {
    const int t = blockIdx.x * blockDim.x + threadIdx.x;  // b*H + h
    const int b = t >> 10, h = t & 1023;
    float4 sv[NSEG];
#pragma unroll
    for (int sg = 0; sg < NSEG; ++sg)
        sv[sg] = *(const float4*)(partials + (((size_t)b * NSEG + sg) * H + h) * 4);
    Q r = {1.f, 0.f, 0.f, 0.f};
#pragma unroll
    for (int sg = 0; sg < NSEG; ++sg) {
        *(float4*)(partials + (((size_t)b * NSEG + sg) * H + h) * 4) =
            make_float4(r.w, r.x, r.y, r.z);   // exclusive prefix
        Q pq = {sv[sg].x, sv[sg].y, sv[sg].z, sv[sg].w};
        r = qmul(pq, r);
    }
    r = qnorm(r);
    float* mf = m_final + (size_t)t * 4;
    mf[0] = r.w; mf[1] = r.x; mf[2] = r.y; mf[3] = r.z;
}

// same mapping as seg_prod; applies prefix, writes bf16 states coalesced.
__global__ __launch_bounds__(256)
void apply_kernel(const float* __restrict__ v, const float* __restrict__ pfx,
                  unsigned short* __restrict__ st, int S, int H) {
    const int b  = blockIdx.z;
    const int h  = blockIdx.y * 64 + (threadIdx.x & 63);
    const int sg = blockIdx.x * 4 + (threadIdx.x >> 6);
    const int s0 = sg * SEG;
    const size_t vstep = (size_t)3 * H;
    const size_t sstep = (size_t)4 * H;
    const float* vp = v + ((size_t)b * S + s0) * vstep + (size_t)h * 3;
    unsigned short* sp = st + ((size_t)b * S + s0) * sstep + (size_t)h * 4;

    float4 p = *(const float4*)(pfx + (((size_t)b * NSEG + sg) * H + h) * 4);
    Q R = {p.x, p.y, p.z, p.w};

    constexpr int CH = 8;
    float ax[CH], ay[CH], az[CH], bx[CH], by[CH], bz[CH];
#pragma unroll
    for (int i = 0; i < CH; ++i) {
        ax[i] = vp[i * vstep + 0]; ay[i] = vp[i * vstep + 1]; az[i] = vp[i * vstep + 2];
    }
    const int NC = SEG / CH;
    for (int cc = 0; cc < NC; cc += 2) {
        if (cc + 1 < NC) {
            const float* pp = vp + (size_t)(cc + 1) * CH * vstep;
#pragma unroll
            for (int i = 0; i < CH; ++i) {
                bx[i] = pp[i * vstep + 0]; by[i] = pp[i * vstep + 1]; bz[i] = pp[i * vstep + 2];
            }
        }
#pragma unroll
        for (int i = 0; i < CH; ++i) {
            R = qmul(vquat(ax[i], ay[i], az[i]), R);
            Q m = qnorm(R);
            ushort4 u; u.x = f2bf(m.w); u.y = f2bf(m.x); u.z = f2bf(m.y); u.w = f2bf(m.z);
            *(ushort4*)(sp + (size_t)(cc * CH + i) * sstep) = u;
        }
        if (cc + 2 < NC) {
            const float* pp = vp + (size_t)(cc + 2) * CH * vstep;
#pragma unroll
            for (int i = 0; i < CH; ++i) {
                ax[i] = pp[i * vstep + 0]; ay[i] = pp[i * vstep + 1]; az[i] = pp[i * vstep + 2];
            }
        }
#pragma unroll
        for (int i = 0; i < CH; ++i) {
            R = qmul(vquat(bx[i], by[i], bz[i]), R);
            Q m = qnorm(R);
            ushort4 u; u.x = f2bf(m.w); u.y = f2bf(m.x); u.z = f2bf(m.y); u.w = f2bf(m.z);
            *(ushort4*)(sp + (size_t)((cc + 1) * CH + i) * sstep) = u;
        }
    }
}

// ---------------- launch ----------------

extern "C" void kernel_launch(void* const* d_in, const int* in_sizes, int n_in,
                              void* d_out, int out_size, void* d_ws, size_t ws_size,
                              hipStream_t stream) {
    const float* x     = (const float*)d_in[0];
    const float* W_in  = (const float*)d_in[1];
    const float* b_in  = (const float*)d_in[2];
    const float* W_out = (const float*)d_in[3];
    const float* b_out = (const float*)d_in[4];
    float* out = (float*)d_out;

    const int B = 4, S = 2048, D = 1024, H = 1024;
    const int M  = B * S;    // 8192
    const int N1 = 3 * H;    // 3072
    const int K1 = D;        // 1024
    const int N2 = D;        // 1024
    const int K2 = 4 * H;    // 4096

    char* ws = (char*)d_ws;
    float*          v    = (float*)(ws);                        // 96 MB
    unsigned short* st   = (unsigned short*)(ws + 100663296u);  // 64 MB (after GEMM1)
    unsigned short* xh16 = (unsigned short*)(ws + 100663296u);  // consumed by GEMM1
    unsigned short* xl16 = (unsigned short*)(ws + 100663296u + 16777216u);
    unsigned short* wi16 = (unsigned short*)(ws + 100663296u + 33554432u);
    unsigned short* woh  = (unsigned short*)(ws + 167772160u);  // 8 MB, lives to GEMM2

    // partials (2 MB) live in d_out — free until GEMM2 overwrites it last.
    float* partials = out;

    const int nx  = M * K1;    // 8388608
    const int nw  = N1 * K1;   // 3145728
    const int nwo = N2 * K2;   // 4194304
    const int ntot = nx + nw + nwo;

    prep_kernel<<<(ntot + 255) / 256, 256, 0, stream>>>(
        x, xh16, xl16, W_in, wi16, W_out, woh, nx, nw, nwo);

    // v = x @ W_in^T + b_in   (fp16 split-A, 2 MFMAs/k-step)
    gemm_bt<128, 128, 32, true, true><<<dim3(N1 / 128, M / 128), 256, 24576, stream>>>(
        xh16, xl16, wi16, b_in, v, M, N1, K1);

    // hierarchical scan
    dim3 sg_grid(NSEG / 4, H / 64, B);
    seg_prod_kernel<<<sg_grid, 256, 0, stream>>>(v, partials, S, H);
    seg_scan_kernel<<<(B * H) / 256, 256, 0, stream>>>(partials, out + (size_t)M * D, H);
    apply_kernel<<<sg_grid, 256, 0, stream>>>(v, partials, st, S, H);

    // out = states @ W_out^T + b_out  (bf16; BM=64 -> 1024 blocks = 4/CU)
    gemm_bt<64, 128, 64, false, false><<<dim3(N2 / 128, M / 64), 256, 24576, stream>>>(
        st, nullptr, woh, b_out, out, M, N2, K2);
}

// Round 6
// 377.259 us; speedup vs baseline: 2.4021x; 1.0959x over previous
//
#include <hip/hip_runtime.h>
#include <hip/hip_bf16.h>
#include <stdint.h>

#define EPSF 1e-8f

typedef __attribute__((ext_vector_type(8))) short short8;
typedef __attribute__((ext_vector_type(8))) _Float16 half8;
typedef __attribute__((ext_vector_type(4))) float floatx4;

__device__ __forceinline__ unsigned short f2bf(float f) {
    union { float f; unsigned u; } c; c.f = f;
    unsigned u = c.u;
    unsigned r = u >> 16;
    unsigned rem = u & 0xffffu;
    r += (rem > 0x8000u) || ((rem == 0x8000u) && (r & 1u));
    return (unsigned short)r;
}
__device__ __forceinline__ unsigned short f2h(float f) {
    _Float16 h = (_Float16)f;
    return __builtin_bit_cast(unsigned short, h);
}
__device__ __forceinline__ float h2f(unsigned short u) {
    return (float)__builtin_bit_cast(_Float16, u);
}

// ---------------- fused conversion kernel ----------------

__global__ void prep_kernel(const float* __restrict__ x,
                            unsigned short* __restrict__ xh, unsigned short* __restrict__ xl,
                            const float* __restrict__ wi, unsigned short* __restrict__ wi16,
                            const float* __restrict__ wo, unsigned short* __restrict__ woh,
                            int nx, int nw, int nwo) {
    int i = blockIdx.x * blockDim.x + threadIdx.x;
    if (i < nx) {
        float f = x[i];
        unsigned short h = f2h(f);
        xh[i] = h;
        xl[i] = f2h(f - h2f(h));
    } else if (i < nx + nw) {
        int j = i - nx;
        wi16[j] = f2h(wi[j]);
    } else if (i < nx + nw + nwo) {
        int j = i - nx - nw;
        woh[j] = f2bf(wo[j]);
    }
}

// ---------------- MFMA GEMM (C = A * B^T + bias) ----------------
// XOR-swizzled LDS: slot r*CPR+cc holds global 16B chunk cc^(r&(CPR-1)).
// With CPR=8 (BK=64) a quad-phase's 16 lanes sweep all 8 bank groups ->
// conflict-free (2 lanes/group is free per m136). Without this, BK=64's
// 128B row stride = exact bank wrap -> 16-way conflict (r5: 3.8e7 cycles).

__device__ __forceinline__ void gld16(const unsigned short* g, unsigned short* l) {
    __builtin_amdgcn_global_load_lds(
        (const __attribute__((address_space(1))) unsigned int*)g,
        (__attribute__((address_space(3))) unsigned int*)l, 16, 0, 0);
}

template <bool FP16>
__device__ __forceinline__ floatx4 mfma16(short8 a, short8 b, floatx4 c) {
    if constexpr (FP16) {
        return __builtin_amdgcn_mfma_f32_16x16x32_f16(
            __builtin_bit_cast(half8, a), __builtin_bit_cast(half8, b), c, 0, 0, 0);
    } else {
        return __builtin_amdgcn_mfma_f32_16x16x32_bf16(a, b, c, 0, 0, 0);
    }
}

template <int BM, int BN, int BK, bool SPLITA, bool FP16>
__global__ __launch_bounds__(256)
void gemm_bt(const unsigned short* __restrict__ Ah, const unsigned short* __restrict__ Al,
             const unsigned short* __restrict__ Bm,
             const float* __restrict__ bias, float* __restrict__ C,
             int M, int N, int K) {
    constexpr int IF  = BM / 32;       // row fragments per wave (waves 2x2)
    constexpr int JF  = BN / 32;       // col fragments per wave
    constexpr int KH  = BK / 32;       // mfma k-steps per tile
    constexpr int CPR = BK / 8;        // 16B chunks per row
    extern __shared__ unsigned short smem[];
    unsigned short* sAh = smem;
    unsigned short* sAl = smem + BM * BK;                    // when SPLITA
    unsigned short* sB  = smem + (SPLITA ? 2 : 1) * BM * BK;

    const int tid  = threadIdx.x;
    const int lane = tid & 63;
    const int wid  = tid >> 6;
    const int wr   = wid >> 1, wc = wid & 1;
    const int m16  = lane & 15, quad = lane >> 4;

    const int rowA0 = blockIdx.y * BM;
    const int rowB0 = blockIdx.x * BN;

    floatx4 acc[IF][JF];
#pragma unroll
    for (int i = 0; i < IF; i++)
#pragma unroll
        for (int j = 0; j < JF; j++) acc[i][j] = (floatx4){0.f, 0.f, 0.f, 0.f};

    const int nk = K / BK;
    for (int kt = 0; kt < nk; ++kt) {
        const int k0 = kt * BK;
#pragma unroll
        for (int i = 0; i < BM * CPR / 256; i++) {
            int c = tid + 256 * i;
            int r = c / CPR, ccl = c % CPR;
            int ccg = ccl ^ (r & (CPR - 1));   // swizzled source chunk
            gld16(Ah + (size_t)(rowA0 + r) * K + k0 + ccg * 8, sAh + c * 8);
            if (SPLITA)
                gld16(Al + (size_t)(rowA0 + r) * K + k0 + ccg * 8, sAl + c * 8);
        }
#pragma unroll
        for (int i = 0; i < BN * CPR / 256; i++) {
            int c = tid + 256 * i;
            int r = c / CPR, ccl = c % CPR;
            int ccg = ccl ^ (r & (CPR - 1));
            gld16(Bm + (size_t)(rowB0 + r) * K + k0 + ccg * 8, sB + c * 8);
        }
        __syncthreads();

#pragma unroll
        for (int kh = 0; kh < KH; kh++) {
            short8 a[IF], al[IF], b[JF];
            const int kc = kh * 4 + quad;
#pragma unroll
            for (int i = 0; i < IF; i++) {
                int ra = wr * (BM / 2) + i * 16 + m16;
                int pa = ra * CPR + (kc ^ (ra & (CPR - 1)));
                a[i] = *(const short8*)(sAh + pa * 8);
                if (SPLITA)
                    al[i] = *(const short8*)(sAl + pa * 8);
            }
#pragma unroll
            for (int j = 0; j < JF; j++) {
                int rb = wc * (BN / 2) + j * 16 + m16;
                int pb = rb * CPR + (kc ^ (rb & (CPR - 1)));
                b[j] = *(const short8*)(sB + pb * 8);
            }
#pragma unroll
            for (int i = 0; i < IF; i++)
#pragma unroll
                for (int j = 0; j < JF; j++) {
                    acc[i][j] = mfma16<FP16>(a[i], b[j], acc[i][j]);
                    if (SPLITA)
                        acc[i][j] = mfma16<FP16>(al[i], b[j], acc[i][j]);
                }
        }
        __syncthreads();
    }

    // C/D layout: col=lane&15, row=quad*4+reg (verified m89/m91)
#pragma unroll
    for (int i = 0; i < IF; i++) {
#pragma unroll
        for (int j = 0; j < JF; j++) {
            int col  = rowB0 + wc * (BN / 2) + j * 16 + m16;
            float bv = bias[col];
#pragma unroll
            for (int r = 0; r < 4; r++) {
                int row = rowA0 + wr * (BM / 2) + i * 16 + quad * 4 + r;
                C[(size_t)row * N + col] = acc[i][j][r] + bv;
            }
        }
    }
}

// ---------------- hierarchical quaternion prefix-product scan ----------------

struct Q { float w, x, y, z; };

__device__ __forceinline__ Q qmul(Q a, Q b) {   // a later (left), b earlier
    Q r;
    r.w = a.w * b.w - a.x * b.x - a.y * b.y - a.z * b.z;
    r.x = a.w * b.x + a.x * b.w + a.y * b.z - a.z * b.y;
    r.y = a.w * b.y - a.x * b.z + a.y * b.w + a.z * b.x;
    r.z = a.w * b.z + a.x * b.y - a.y * b.x + a.z * b.w;
    return r;
}
__device__ __forceinline__ Q qnorm(Q a) {
    float nn = a.w * a.w + a.x * a.x + a.y * a.y + a.z * a.z;
    float inv = __frsqrt_rn(nn);
    Q r; r.w = a.w * inv; r.x = a.x * inv; r.y = a.y * inv; r.z = a.z * inv;
    return r;
}
__device__ __forceinline__ Q vquat(float vx, float vy, float vz) {
    float th = sqrtf(vx * vx + vy * vy + vz * vz);
    float s_, c_;
    __sincosf(th, &s_, &c_);
    float k = __fdividef(s_, th + EPSF);
    Q q; q.w = c_; q.x = k * vx; q.y = k * vy; q.z = k * vz;
    return q;
}

#define SEG  64
#define NSEG 32

// block: 256 thr = 64 h x 4 segments; grid (NSEG/4, H/64, B)
__global__ __launch_bounds__(256)
void seg_prod_kernel(const float* __restrict__ v, float* __restrict__ partials,
                     int S, int H) {
    const int b  = blockIdx.z;
    const int h  = blockIdx.y * 64 + (threadIdx.x & 63);
    const int sg = blockIdx.x * 4 + (threadIdx.x >> 6);
    const int s0 = sg * SEG;
    const size_t vstep = (size_t)3 * H;
    const float* vp = v + ((size_t)b * S + s0) * vstep + (size_t)h * 3;

    constexpr int CH = 8;
    float ax[CH], ay[CH], az[CH], bx[CH], by[CH], bz[CH];
#pragma unroll
    for (int i = 0; i < CH; ++i) {
        ax[i] = vp[i * vstep + 0]; ay[i] = vp[i * vstep + 1]; az[i] = vp[i * vstep + 2];
    }
    Q c = {1.f, 0.f, 0.f, 0.f};
    const int NC = SEG / CH;  // 8 chunks
    for (int cc = 0; cc < NC; cc += 2) {
        if (cc + 1 < NC) {
            const float* p = vp + (size_t)(cc + 1) * CH * vstep;
#pragma unroll
            for (int i = 0; i < CH; ++i) {
                bx[i] = p[i * vstep + 0]; by[i] = p[i * vstep + 1]; bz[i] = p[i * vstep + 2];
            }
        }
#pragma unroll
        for (int i = 0; i < CH; ++i) c = qmul(vquat(ax[i], ay[i], az[i]), c);
        if (cc + 2 < NC) {
            const float* p = vp + (size_t)(cc + 2) * CH * vstep;
#pragma unroll
            for (int i = 0; i < CH; ++i) {
                ax[i] = p[i * vstep + 0]; ay[i] = p[i * vstep + 1]; az[i] = p[i * vstep + 2];
            }
        }
#pragma unroll
        for (int i = 0; i < CH; ++i) c = qmul(vquat(bx[i], by[i], bz[i]), c);
    }
    float4* dst = (float4*)(partials + (((size_t)b * NSEG + sg) * H + h) * 4);
    *dst = make_float4(c.w, c.x, c.y, c.z);
}

// 4096 threads, one per chain; batch-load all segments, exclusive scan.
__global__ __launch_bounds__(256)
void seg_scan_kernel(float* __restrict__ partials, float* __restrict__ m_final, int H) {
    const int t = blockIdx.x * blockDim.x + threadIdx.x;  // b*H + h
    const int b = t >> 10, h = t & 1023;
    float4 sv[NSEG];
#pragma unroll
    for (int sg = 0; sg < NSEG; ++sg)
        sv[sg] = *(const float4*)(partials + (((size_t)b * NSEG + sg) * H + h) * 4);
    Q r = {1.f, 0.f, 0.f, 0.f};
#pragma unroll
    for (int sg = 0; sg < NSEG; ++sg) {
        *(float4*)(partials + (((size_t)b * NSEG + sg) * H + h) * 4) =
            make_float4(r.w, r.x, r.y, r.z);   // exclusive prefix
        Q pq = {sv[sg].x, sv[sg].y, sv[sg].z, sv[sg].w};
        r = qmul(pq, r);
    }
    r = qnorm(r);
    float* mf = m_final + (size_t)t * 4;
    mf[0] = r.w; mf[1] = r.x; mf[2] = r.y; mf[3] = r.z;
}

// same mapping as seg_prod; applies prefix, writes bf16 states coalesced.
__global__ __launch_bounds__(256)
void apply_kernel(const float* __restrict__ v, const float* __restrict__ pfx,
                  unsigned short* __restrict__ st, int S, int H) {
    const int b  = blockIdx.z;
    const int h  = blockIdx.y * 64 + (threadIdx.x & 63);
    const int sg = blockIdx.x * 4 + (threadIdx.x >> 6);
    const int s0 = sg * SEG;
    const size_t vstep = (size_t)3 * H;
    const size_t sstep = (size_t)4 * H;
    const float* vp = v + ((size_t)b * S + s0) * vstep + (size_t)h * 3;
    unsigned short* sp = st + ((size_t)b * S + s0) * sstep + (size_t)h * 4;

    float4 p = *(const float4*)(pfx + (((size_t)b * NSEG + sg) * H + h) * 4);
    Q R = {p.x, p.y, p.z, p.w};

    constexpr int CH = 8;
    float ax[CH], ay[CH], az[CH], bx[CH], by[CH], bz[CH];
#pragma unroll
    for (int i = 0; i < CH; ++i) {
        ax[i] = vp[i * vstep + 0]; ay[i] = vp[i * vstep + 1]; az[i] = vp[i * vstep + 2];
    }
    const int NC = SEG / CH;
    for (int cc = 0; cc < NC; cc += 2) {
        if (cc + 1 < NC) {
            const float* pp = vp + (size_t)(cc + 1) * CH * vstep;
#pragma unroll
            for (int i = 0; i < CH; ++i) {
                bx[i] = pp[i * vstep + 0]; by[i] = pp[i * vstep + 1]; bz[i] = pp[i * vstep + 2];
            }
        }
#pragma unroll
        for (int i = 0; i < CH; ++i) {
            R = qmul(vquat(ax[i], ay[i], az[i]), R);
            Q m = qnorm(R);
            ushort4 u; u.x = f2bf(m.w); u.y = f2bf(m.x); u.z = f2bf(m.y); u.w = f2bf(m.z);
            *(ushort4*)(sp + (size_t)(cc * CH + i) * sstep) = u;
        }
        if (cc + 2 < NC) {
            const float* pp = vp + (size_t)(cc + 2) * CH * vstep;
#pragma unroll
            for (int i = 0; i < CH; ++i) {
                ax[i] = pp[i * vstep + 0]; ay[i] = pp[i * vstep + 1]; az[i] = pp[i * vstep + 2];
            }
        }
#pragma unroll
        for (int i = 0; i < CH; ++i) {
            R = qmul(vquat(bx[i], by[i], bz[i]), R);
            Q m = qnorm(R);
            ushort4 u; u.x = f2bf(m.w); u.y = f2bf(m.x); u.z = f2bf(m.y); u.w = f2bf(m.z);
            *(ushort4*)(sp + (size_t)((cc + 1) * CH + i) * sstep) = u;
        }
    }
}

// ---------------- launch ----------------

extern "C" void kernel_launch(void* const* d_in, const int* in_sizes, int n_in,
                              void* d_out, int out_size, void* d_ws, size_t ws_size,
                              hipStream_t stream) {
    const float* x     = (const float*)d_in[0];
    const float* W_in  = (const float*)d_in[1];
    const float* b_in  = (const float*)d_in[2];
    const float* W_out = (const float*)d_in[3];
    const float* b_out = (const float*)d_in[4];
    float* out = (float*)d_out;

    const int B = 4, S = 2048, D = 1024, H = 1024;
    const int M  = B * S;    // 8192
    const int N1 = 3 * H;    // 3072
    const int K1 = D;        // 1024
    const int N2 = D;        // 1024
    const int K2 = 4 * H;    // 4096

    char* ws = (char*)d_ws;
    float*          v    = (float*)(ws);                        // 96 MB
    unsigned short* st   = (unsigned short*)(ws + 100663296u);  // 64 MB (after GEMM1)
    unsigned short* xh16 = (unsigned short*)(ws + 100663296u);  // consumed by GEMM1
    unsigned short* xl16 = (unsigned short*)(ws + 100663296u + 16777216u);
    unsigned short* wi16 = (unsigned short*)(ws + 100663296u + 33554432u);
    unsigned short* woh  = (unsigned short*)(ws + 167772160u);  // 8 MB, lives to GEMM2

    // partials (2 MB) live in d_out — free until GEMM2 overwrites it last.
    float* partials = out;

    const int nx  = M * K1;    // 8388608
    const int nw  = N1 * K1;   // 3145728
    const int nwo = N2 * K2;   // 4194304
    const int ntot = nx + nw + nwo;

    prep_kernel<<<(ntot + 255) / 256, 256, 0, stream>>>(
        x, xh16, xl16, W_in, wi16, W_out, woh, nx, nw, nwo);

    // v = x @ W_in^T + b_in   (fp16 split-A, 2 MFMAs/k-step, BK=64 swizzled)
    gemm_bt<128, 128, 64, true, true><<<dim3(N1 / 128, M / 128), 256, 49152, stream>>>(
        xh16, xl16, wi16, b_in, v, M, N1, K1);

    // hierarchical scan
    dim3 sg_grid(NSEG / 4, H / 64, B);
    seg_prod_kernel<<<sg_grid, 256, 0, stream>>>(v, partials, S, H);
    seg_scan_kernel<<<(B * H) / 256, 256, 0, stream>>>(partials, out + (size_t)M * D, H);
    apply_kernel<<<sg_grid, 256, 0, stream>>>(v, partials, st, S, H);

    // out = states @ W_out^T + b_out  (bf16, 128x128 BK=64 swizzled)
    gemm_bt<128, 128, 64, false, false><<<dim3(N2 / 128, M / 128), 256, 32768, stream>>>(
        st, nullptr, woh, b_out, out, M, N2, K2);
}

// Round 7
// 344.403 us; speedup vs baseline: 2.6313x; 1.0954x over previous
//
#include <hip/hip_runtime.h>
#include <hip/hip_bf16.h>
#include <stdint.h>

#define EPSF 1e-8f

typedef __attribute__((ext_vector_type(8))) short short8;
typedef __attribute__((ext_vector_type(8))) _Float16 half8;
typedef __attribute__((ext_vector_type(4))) float floatx4;

__device__ __forceinline__ unsigned short f2h(float f) {
    _Float16 h = (_Float16)f;
    return __builtin_bit_cast(unsigned short, h);
}

// ---------------- fused conversion kernel ----------------
// x -> fp16, W_in -> fp16, W_out -> fp16

__global__ void prep_kernel(const float* __restrict__ x, unsigned short* __restrict__ x16,
                            const float* __restrict__ wi, unsigned short* __restrict__ wi16,
                            const float* __restrict__ wo, unsigned short* __restrict__ wo16,
                            int nx, int nw, int nwo) {
    int i = blockIdx.x * blockDim.x + threadIdx.x;
    if (i < nx) {
        x16[i] = f2h(x[i]);
    } else if (i < nx + nw) {
        int j = i - nx;
        wi16[j] = f2h(wi[j]);
    } else if (i < nx + nw + nwo) {
        int j = i - nx - nw;
        wo16[j] = f2h(wo[j]);
    }
}

// ---------------- MFMA GEMM (C = A * B^T + bias), fp16 ----------------
// XOR-swizzled LDS: slot r*CPR+cc holds global 16B chunk cc^(r&(CPR-1)).
// With CPR=8 (BK=64) a quad-phase's 16 lanes sweep all 8 bank groups ->
// conflict-free (verified r6: SQ_LDS_BANK_CONFLICT = 0).

__device__ __forceinline__ void gld16(const unsigned short* g, unsigned short* l) {
    __builtin_amdgcn_global_load_lds(
        (const __attribute__((address_space(1))) unsigned int*)g,
        (__attribute__((address_space(3))) unsigned int*)l, 16, 0, 0);
}

template <int BM, int BN, int BK>
__global__ __launch_bounds__(256)
void gemm_bt(const unsigned short* __restrict__ Am, const unsigned short* __restrict__ Bm,
             const float* __restrict__ bias, float* __restrict__ C,
             int M, int N, int K) {
    constexpr int IF  = BM / 32;       // row fragments per wave (waves 2x2)
    constexpr int JF  = BN / 32;       // col fragments per wave
    constexpr int KH  = BK / 32;       // mfma k-steps per tile
    constexpr int CPR = BK / 8;        // 16B chunks per row
    extern __shared__ unsigned short smem[];
    unsigned short* sA = smem;
    unsigned short* sB = smem + BM * BK;

    const int tid  = threadIdx.x;
    const int lane = tid & 63;
    const int wid  = tid >> 6;
    const int wr   = wid >> 1, wc = wid & 1;
    const int m16  = lane & 15, quad = lane >> 4;

    const int rowA0 = blockIdx.y * BM;
    const int rowB0 = blockIdx.x * BN;

    floatx4 acc[IF][JF];
#pragma unroll
    for (int i = 0; i < IF; i++)
#pragma unroll
        for (int j = 0; j < JF; j++) acc[i][j] = (floatx4){0.f, 0.f, 0.f, 0.f};

    const int nk = K / BK;
    for (int kt = 0; kt < nk; ++kt) {
        const int k0 = kt * BK;
#pragma unroll
        for (int i = 0; i < BM * CPR / 256; i++) {
            int c = tid + 256 * i;
            int r = c / CPR, ccl = c % CPR;
            int ccg = ccl ^ (r & (CPR - 1));   // swizzled source chunk
            gld16(Am + (size_t)(rowA0 + r) * K + k0 + ccg * 8, sA + c * 8);
        }
#pragma unroll
        for (int i = 0; i < BN * CPR / 256; i++) {
            int c = tid + 256 * i;
            int r = c / CPR, ccl = c % CPR;
            int ccg = ccl ^ (r & (CPR - 1));
            gld16(Bm + (size_t)(rowB0 + r) * K + k0 + ccg * 8, sB + c * 8);
        }
        __syncthreads();

#pragma unroll
        for (int kh = 0; kh < KH; kh++) {
            short8 a[IF], b[JF];
            const int kc = kh * 4 + quad;
#pragma unroll
            for (int i = 0; i < IF; i++) {
                int ra = wr * (BM / 2) + i * 16 + m16;
                int pa = ra * CPR + (kc ^ (ra & (CPR - 1)));
                a[i] = *(const short8*)(sA + pa * 8);
            }
#pragma unroll
            for (int j = 0; j < JF; j++) {
                int rb = wc * (BN / 2) + j * 16 + m16;
                int pb = rb * CPR + (kc ^ (rb & (CPR - 1)));
                b[j] = *(const short8*)(sB + pb * 8);
            }
#pragma unroll
            for (int i = 0; i < IF; i++)
#pragma unroll
                for (int j = 0; j < JF; j++)
                    acc[i][j] = __builtin_amdgcn_mfma_f32_16x16x32_f16(
                        __builtin_bit_cast(half8, a[i]), __builtin_bit_cast(half8, b[j]),
                        acc[i][j], 0, 0, 0);
        }
        __syncthreads();
    }

    // C/D layout: col=lane&15, row=quad*4+reg (verified m89/m91)
#pragma unroll
    for (int i = 0; i < IF; i++) {
#pragma unroll
        for (int j = 0; j < JF; j++) {
            int col  = rowB0 + wc * (BN / 2) + j * 16 + m16;
            float bv = bias[col];
#pragma unroll
            for (int r = 0; r < 4; r++) {
                int row = rowA0 + wr * (BM / 2) + i * 16 + quad * 4 + r;
                C[(size_t)row * N + col] = acc[i][j][r] + bv;
            }
        }
    }
}

// ---------------- hierarchical quaternion prefix-product scan ----------------

struct Q { float w, x, y, z; };

__device__ __forceinline__ Q qmul(Q a, Q b) {   // a later (left), b earlier
    Q r;
    r.w = a.w * b.w - a.x * b.x - a.y * b.y - a.z * b.z;
    r.x = a.w * b.x + a.x * b.w + a.y * b.z - a.z * b.y;
    r.y = a.w * b.y - a.x * b.z + a.y * b.w + a.z * b.x;
    r.z = a.w * b.z + a.x * b.y - a.y * b.x + a.z * b.w;
    return r;
}
__device__ __forceinline__ Q qnorm(Q a) {
    float nn = a.w * a.w + a.x * a.x + a.y * a.y + a.z * a.z;
    float inv = __frsqrt_rn(nn);
    Q r; r.w = a.w * inv; r.x = a.x * inv; r.y = a.y * inv; r.z = a.z * inv;
    return r;
}
__device__ __forceinline__ Q vquat(float vx, float vy, float vz) {
    float th = sqrtf(vx * vx + vy * vy + vz * vz);
    float s_, c_;
    __sincosf(th, &s_, &c_);
    float k = __fdividef(s_, th + EPSF);
    Q q; q.w = c_; q.x = k * vx; q.y = k * vy; q.z = k * vz;
    return q;
}

#define SEG  64
#define NSEG 32

// block: 256 thr = 64 h x 4 segments; grid (NSEG/4, H/64, B)
__global__ __launch_bounds__(256)
void seg_prod_kernel(const float* __restrict__ v, float* __restrict__ partials,
                     int S, int H) {
    const int b  = blockIdx.z;
    const int h  = blockIdx.y * 64 + (threadIdx.x & 63);
    const int sg = blockIdx.x * 4 + (threadIdx.x >> 6);
    const int s0 = sg * SEG;
    const size_t vstep = (size_t)3 * H;
    const float* vp = v + ((size_t)b * S + s0) * vstep + (size_t)h * 3;

    constexpr int CH = 8;
    float ax[CH], ay[CH], az[CH], bx[CH], by[CH], bz[CH];
#pragma unroll
    for (int i = 0; i < CH; ++i) {
        ax[i] = vp[i * vstep + 0]; ay[i] = vp[i * vstep + 1]; az[i] = vp[i * vstep + 2];
    }
    Q c = {1.f, 0.f, 0.f, 0.f};
    const int NC = SEG / CH;  // 8 chunks
    for (int cc = 0; cc < NC; cc += 2) {
        if (cc + 1 < NC) {
            const float* p = vp + (size_t)(cc + 1) * CH * vstep;
#pragma unroll
            for (int i = 0; i < CH; ++i) {
                bx[i] = p[i * vstep + 0]; by[i] = p[i * vstep + 1]; bz[i] = p[i * vstep + 2];
            }
        }
#pragma unroll
        for (int i = 0; i < CH; ++i) c = qmul(vquat(ax[i], ay[i], az[i]), c);
        if (cc + 2 < NC) {
            const float* p = vp + (size_t)(cc + 2) * CH * vstep;
#pragma unroll
            for (int i = 0; i < CH; ++i) {
                ax[i] = p[i * vstep + 0]; ay[i] = p[i * vstep + 1]; az[i] = p[i * vstep + 2];
            }
        }
#pragma unroll
        for (int i = 0; i < CH; ++i) c = qmul(vquat(bx[i], by[i], bz[i]), c);
    }
    float4* dst = (float4*)(partials + (((size_t)b * NSEG + sg) * H + h) * 4);
    *dst = make_float4(c.w, c.x, c.y, c.z);
}

// 4096 threads, one per chain; batch-load all segments, exclusive scan.
__global__ __launch_bounds__(256)
void seg_scan_kernel(float* __restrict__ partials, float* __restrict__ m_final, int H) {
    const int t = blockIdx.x * blockDim.x + threadIdx.x;  // b*H + h
    const int b = t >> 10, h = t & 1023;
    float4 sv[NSEG];
#pragma unroll
    for (int sg = 0; sg < NSEG; ++sg)
        sv[sg] = *(const float4*)(partials + (((size_t)b * NSEG + sg) * H + h) * 4);
    Q r = {1.f, 0.f, 0.f, 0.f};
#pragma unroll
    for (int sg = 0; sg < NSEG; ++sg) {
        *(float4*)(partials + (((size_t)b * NSEG + sg) * H + h) * 4) =
            make_float4(r.w, r.x, r.y, r.z);   // exclusive prefix
        Q pq = {sv[sg].x, sv[sg].y, sv[sg].z, sv[sg].w};
        r = qmul(pq, r);
    }
    r = qnorm(r);
    float* mf = m_final + (size_t)t * 4;
    mf[0] = r.w; mf[1] = r.x; mf[2] = r.y; mf[3] = r.z;
}

// same mapping as seg_prod; applies prefix, writes fp16 states coalesced.
__global__ __launch_bounds__(256)
void apply_kernel(const float* __restrict__ v, const float* __restrict__ pfx,
                  unsigned short* __restrict__ st, int S, int H) {
    const int b  = blockIdx.z;
    const int h  = blockIdx.y * 64 + (threadIdx.x & 63);
    const int sg = blockIdx.x * 4 + (threadIdx.x >> 6);
    const int s0 = sg * SEG;
    const size_t vstep = (size_t)3 * H;
    const size_t sstep = (size_t)4 * H;
    const float* vp = v + ((size_t)b * S + s0) * vstep + (size_t)h * 3;
    unsigned short* sp = st + ((size_t)b * S + s0) * sstep + (size_t)h * 4;

    float4 p = *(const float4*)(pfx + (((size_t)b * NSEG + sg) * H + h) * 4);
    Q R = {p.x, p.y, p.z, p.w};

    constexpr int CH = 8;
    float ax[CH], ay[CH], az[CH], bx[CH], by[CH], bz[CH];
#pragma unroll
    for (int i = 0; i < CH; ++i) {
        ax[i] = vp[i * vstep + 0]; ay[i] = vp[i * vstep + 1]; az[i] = vp[i * vstep + 2];
    }
    const int NC = SEG / CH;
    for (int cc = 0; cc < NC; cc += 2) {
        if (cc + 1 < NC) {
            const float* pp = vp + (size_t)(cc + 1) * CH * vstep;
#pragma unroll
            for (int i = 0; i < CH; ++i) {
                bx[i] = pp[i * vstep + 0]; by[i] = pp[i * vstep + 1]; bz[i] = pp[i * vstep + 2];
            }
        }
#pragma unroll
        for (int i = 0; i < CH; ++i) {
            R = qmul(vquat(ax[i], ay[i], az[i]), R);
            Q m = qnorm(R);
            ushort4 u; u.x = f2h(m.w); u.y = f2h(m.x); u.z = f2h(m.y); u.w = f2h(m.z);
            *(ushort4*)(sp + (size_t)(cc * CH + i) * sstep) = u;
        }
        if (cc + 2 < NC) {
            const float* pp = vp + (size_t)(cc + 2) * CH * vstep;
#pragma unroll
            for (int i = 0; i < CH; ++i) {
                ax[i] = pp[i * vstep + 0]; ay[i] = pp[i * vstep + 1]; az[i] = pp[i * vstep + 2];
            }
        }
#pragma unroll
        for (int i = 0; i < CH; ++i) {
            R = qmul(vquat(bx[i], by[i], bz[i]), R);
            Q m = qnorm(R);
            ushort4 u; u.x = f2h(m.w); u.y = f2h(m.x); u.z = f2h(m.y); u.w = f2h(m.z);
            *(ushort4*)(sp + (size_t)((cc + 1) * CH + i) * sstep) = u;
        }
    }
}

// ---------------- launch ----------------

extern "C" void kernel_launch(void* const* d_in, const int* in_sizes, int n_in,
                              void* d_out, int out_size, void* d_ws, size_t ws_size,
                              hipStream_t stream) {
    const float* x     = (const float*)d_in[0];
    const float* W_in  = (const float*)d_in[1];
    const float* b_in  = (const float*)d_in[2];
    const float* W_out = (const float*)d_in[3];
    const float* b_out = (const float*)d_in[4];
    float* out = (float*)d_out;

    const int B = 4, S = 2048, D = 1024, H = 1024;
    const int M  = B * S;    // 8192
    const int N1 = 3 * H;    // 3072
    const int K1 = D;        // 1024
    const int N2 = D;        // 1024
    const int K2 = 4 * H;    // 4096

    char* ws = (char*)d_ws;
    float*          v    = (float*)(ws);                        // 96 MB
    unsigned short* st   = (unsigned short*)(ws + 100663296u);  // 64 MB (after GEMM1)
    unsigned short* x16  = (unsigned short*)(ws + 100663296u);  // consumed by GEMM1
    unsigned short* wi16 = (unsigned short*)(ws + 100663296u + 16777216u);
    unsigned short* wo16 = (unsigned short*)(ws + 167772160u);  // 8 MB, lives to GEMM2

    // partials (2 MB) live in d_out — free until GEMM2 overwrites it last.
    float* partials = out;

    const int nx  = M * K1;    // 8388608
    const int nw  = N1 * K1;   // 3145728
    const int nwo = N2 * K2;   // 4194304
    const int ntot = nx + nw + nwo;

    prep_kernel<<<(ntot + 255) / 256, 256, 0, stream>>>(
        x, x16, W_in, wi16, W_out, wo16, nx, nw, nwo);

    // v = x @ W_in^T + b_in   (single fp16 MFMA, BK=64 swizzled)
    gemm_bt<128, 128, 64><<<dim3(N1 / 128, M / 128), 256, 32768, stream>>>(
        x16, wi16, b_in, v, M, N1, K1);

    // hierarchical scan
    dim3 sg_grid(NSEG / 4, H / 64, B);
    seg_prod_kernel<<<sg_grid, 256, 0, stream>>>(v, partials, S, H);
    seg_scan_kernel<<<(B * H) / 256, 256, 0, stream>>>(partials, out + (size_t)M * D, H);
    apply_kernel<<<sg_grid, 256, 0, stream>>>(v, partials, st, S, H);

    // out = states @ W_out^T + b_out  (fp16, 128x128 BK=64 swizzled)
    gemm_bt<128, 128, 64><<<dim3(N2 / 128, M / 128), 256, 32768, stream>>>(
        st, wo16, b_out, out, M, N2, K2);
}